// Round 4
// baseline (356.269 us; speedup 1.0000x reference)
//
#include <hip/hip_runtime.h>

#define DEV __device__ __forceinline__

constexpr int Nn = 1024, Tn = 12, Dn = 64;

#if __has_builtin(__builtin_amdgcn_exp2f)
DEV float fast_exp2(float x) { return __builtin_amdgcn_exp2f(x); }
#else
DEV float fast_exp2(float x) { return exp2f(x); }
#endif

DEV void wave_reduce2(float& s, float& s2) {
#pragma unroll
  for (int off = 32; off; off >>= 1) {
    s += __shfl_xor(s, off, 64);
    s2 += __shfl_xor(s2, off, 64);
  }
}

// ---------------------------------------------------------------- pack adj
// adj [1024][1024] i32 -> 64-bit masks, one wave per 64 entries.
__global__ __launch_bounds__(256) void k_pack(const int* __restrict__ adj,
                                              unsigned long long* __restrict__ packed) {
  int gw = (blockIdx.x * 256 + threadIdx.x) >> 6;
  int lane = threadIdx.x & 63;
  int v = adj[(gw << 6) + lane];
  unsigned long long m = __ballot(v != 0);
  if (lane == 0) packed[gw] = m;
}

// ---------------------------------------------------------------- LN1 + QKV
// 4 waves/block, 16 rows/wave; weights LDS-staged; lane = output channel.
__global__ __launch_bounds__(256) void k_ln1_qkv(
    const float* __restrict__ x, const float* __restrict__ wq,
    const float* __restrict__ wk, const float* __restrict__ wv,
    const float* __restrict__ g1, const float* __restrict__ be1,
    float* __restrict__ Q, float* __restrict__ K, float* __restrict__ V) {
  __shared__ float wlds[64 * 192];
  __shared__ float hlds[4][16][68];   // wave-private: same-wave ds ordering suffices
  int tid = threadIdx.x, lane = tid & 63, w = tid >> 6;
  for (int i = tid * 4; i < 4096; i += 1024) {
    int c = i >> 6, d = i & 63;
    *(float4*)&wlds[c * 192 + d]       = *(const float4*)&wq[i];
    *(float4*)&wlds[c * 192 + 64 + d]  = *(const float4*)&wk[i];
    *(float4*)&wlds[c * 192 + 128 + d] = *(const float4*)&wv[i];
  }
  float g = g1[lane], be = be1[lane];
  __syncthreads();
  int row0 = blockIdx.x * 64 + w * 16;
#pragma unroll 1
  for (int r = 0; r < 16; ++r) {
    int row = row0 + r;
    int bt = row >> 10, n = row & 1023;
    int b = bt / Tn, t = bt - b * Tn;
    float xv = x[((b * Nn + n) * Tn + t) * 64 + lane];
    float s = xv, s2 = xv * xv;
    wave_reduce2(s, s2);
    float mean = s * 0.015625f;
    float var = s2 * 0.015625f - mean * mean;
    float rs = rsqrtf(var + 1e-5f);
    hlds[w][r][lane] = (xv - mean) * rs * g + be;
  }
  float qa[16], ka[16], va[16];
#pragma unroll
  for (int r = 0; r < 16; ++r) { qa[r] = 0.f; ka[r] = 0.f; va[r] = 0.f; }
  for (int c = 0; c < 64; c += 4) {
    float wq4[4], wk4[4], wv4[4];
#pragma unroll
    for (int cc = 0; cc < 4; ++cc) {
      wq4[cc] = wlds[(c + cc) * 192 + lane];
      wk4[cc] = wlds[(c + cc) * 192 + 64 + lane];
      wv4[cc] = wlds[(c + cc) * 192 + 128 + lane];
    }
#pragma unroll
    for (int r = 0; r < 16; ++r) {
      float4 h4 = *(float4*)&hlds[w][r][c];
      qa[r] = fmaf(h4.x, wq4[0], qa[r]); qa[r] = fmaf(h4.y, wq4[1], qa[r]);
      qa[r] = fmaf(h4.z, wq4[2], qa[r]); qa[r] = fmaf(h4.w, wq4[3], qa[r]);
      ka[r] = fmaf(h4.x, wk4[0], ka[r]); ka[r] = fmaf(h4.y, wk4[1], ka[r]);
      ka[r] = fmaf(h4.z, wk4[2], ka[r]); ka[r] = fmaf(h4.w, wk4[3], ka[r]);
      va[r] = fmaf(h4.x, wv4[0], va[r]); va[r] = fmaf(h4.y, wv4[1], va[r]);
      va[r] = fmaf(h4.z, wv4[2], va[r]); va[r] = fmaf(h4.w, wv4[3], va[r]);
    }
  }
  const float QS = 0.25f * 1.44269504088896f;  // fold 1/sqrt(HD)=0.25 and log2(e)
#pragma unroll 1
  for (int r = 0; r < 16; ++r) {
    int row = row0 + r;
    int bt = row >> 10, n = row & 1023;
    int hh = lane >> 4, cc = lane & 15;
    int idx = ((bt * 4 + hh) * 1024 + n) * 16 + cc;   // [bt][h][n][hd]
    Q[idx] = qa[r] * QS;
    K[idx] = ka[r];
    V[idx] = va[r];
  }
}

// ---------------------------------------------------------------- attention
// grid: 96 (b,t,h) x 8 qblocks. block = 4 waves: 2 qsubs x 2 key-halves
// (split-K over keys, combined in LDS). Lane owns one query row; K/V chunks
// broadcast-read from LDS (uniform addr = conflict-free).
__global__ __launch_bounds__(256) void k_attn(
    const float* __restrict__ Q, const float* __restrict__ Kg,
    const float* __restrict__ Vg, const unsigned long long* __restrict__ packed,
    float* __restrict__ O) {
  __shared__ float Kt[2][256 * 16];
  __shared__ float Vt[2][256 * 16];
  __shared__ float comb[2][64][18];
  int bth = blockIdx.x >> 3, qb = blockIdx.x & 7;
  int bt = bth >> 2, h = bth & 3;
  int tid = threadIdx.x, lane = tid & 63, w = tid >> 6;
  int qsub = w >> 1, kh = w & 1;
  int nq = qb * 128 + qsub * 64 + lane;
  const float* Qb = Q + bth * 16384;
  const float* Kb = Kg + bth * 16384;
  const float* Vb = Vg + bth * 16384;
  float4 q0 = *(const float4*)&Qb[nq * 16 + 0];
  float4 q1 = *(const float4*)&Qb[nq * 16 + 4];
  float4 q2 = *(const float4*)&Qb[nq * 16 + 8];
  float4 q3 = *(const float4*)&Qb[nq * 16 + 12];
  unsigned long long w8[8];
#pragma unroll
  for (int i = 0; i < 8; ++i) w8[i] = packed[nq * 16 + kh * 8 + i];
  float o[16];
#pragma unroll
  for (int e = 0; e < 16; ++e) o[e] = 0.f;
  float m = -1e38f, l = 0.f;
#pragma unroll 1
  for (int it = 0; it < 2; ++it) {
    __syncthreads();
    {
      int base0 = (it * 256) * 16;          // keys it*256..+255   (kh=0)
      int base1 = (512 + it * 256) * 16;    // keys 512+it*256..   (kh=1)
      for (int i = tid * 4; i < 4096; i += 1024) {
        *(float4*)&Kt[0][i] = *(const float4*)&Kb[base0 + i];
        *(float4*)&Kt[1][i] = *(const float4*)&Kb[base1 + i];
        *(float4*)&Vt[0][i] = *(const float4*)&Vb[base0 + i];
        *(float4*)&Vt[1][i] = *(const float4*)&Vb[base1 + i];
      }
    }
    __syncthreads();
    const float* Kc = Kt[kh];
    const float* Vc = Vt[kh];
#pragma unroll 1
    for (int g = 0; g < 4; ++g) {
      unsigned long long wrd = w8[it * 4 + g];  // keys kh*512+it*256+g*64
#pragma unroll 1
      for (int sg = 0; sg < 4; ++sg) {
        float s[16];
#pragma unroll
        for (int kk = 0; kk < 16; ++kk) {
          const float* kp = &Kc[(g * 64 + sg * 16 + kk) * 16];
          float4 k0 = *(const float4*)&kp[0];
          float4 k1 = *(const float4*)&kp[4];
          float4 k2 = *(const float4*)&kp[8];
          float4 k3 = *(const float4*)&kp[12];
          float a0 = q0.x * k0.x, a1 = q0.y * k0.y, a2 = q0.z * k0.z, a3 = q0.w * k0.w;
          a0 = fmaf(q1.x, k1.x, a0); a1 = fmaf(q1.y, k1.y, a1);
          a2 = fmaf(q1.z, k1.z, a2); a3 = fmaf(q1.w, k1.w, a3);
          a0 = fmaf(q2.x, k2.x, a0); a1 = fmaf(q2.y, k2.y, a1);
          a2 = fmaf(q2.z, k2.z, a2); a3 = fmaf(q2.w, k2.w, a3);
          a0 = fmaf(q3.x, k3.x, a0); a1 = fmaf(q3.y, k3.y, a1);
          a2 = fmaf(q3.z, k3.z, a2); a3 = fmaf(q3.w, k3.w, a3);
          float acc = (a0 + a1) + (a2 + a3);
          s[kk] = ((wrd >> (sg * 16 + kk)) & 1ull) ? acc : -3e38f;
        }
        float cm = fmaxf(fmaxf(fmaxf(s[0], s[1]), fmaxf(s[2], s[3])),
                         fmaxf(fmaxf(s[4], s[5]), fmaxf(s[6], s[7])));
        cm = fmaxf(cm, fmaxf(fmaxf(fmaxf(s[8], s[9]), fmaxf(s[10], s[11])),
                             fmaxf(fmaxf(s[12], s[13]), fmaxf(s[14], s[15]))));
        float mn = fmaxf(m, cm);
        float sc = fast_exp2(m - mn);
        m = mn;
        l *= sc;
#pragma unroll
        for (int e = 0; e < 16; ++e) o[e] *= sc;
#pragma unroll
        for (int kk = 0; kk < 16; ++kk) {
          float p = fast_exp2(s[kk] - m);
          l += p;
          const float* vp = &Vc[(g * 64 + sg * 16 + kk) * 16];
          float4 v0 = *(const float4*)&vp[0];
          float4 v1 = *(const float4*)&vp[4];
          float4 v2 = *(const float4*)&vp[8];
          float4 v3 = *(const float4*)&vp[12];
          o[0] = fmaf(p, v0.x, o[0]);  o[1] = fmaf(p, v0.y, o[1]);
          o[2] = fmaf(p, v0.z, o[2]);  o[3] = fmaf(p, v0.w, o[3]);
          o[4] = fmaf(p, v1.x, o[4]);  o[5] = fmaf(p, v1.y, o[5]);
          o[6] = fmaf(p, v1.z, o[6]);  o[7] = fmaf(p, v1.w, o[7]);
          o[8] = fmaf(p, v2.x, o[8]);  o[9] = fmaf(p, v2.y, o[9]);
          o[10] = fmaf(p, v2.z, o[10]); o[11] = fmaf(p, v2.w, o[11]);
          o[12] = fmaf(p, v3.x, o[12]); o[13] = fmaf(p, v3.y, o[13]);
          o[14] = fmaf(p, v3.z, o[14]); o[15] = fmaf(p, v3.w, o[15]);
        }
      }
    }
  }
  if (kh == 1) {
#pragma unroll
    for (int e = 0; e < 16; ++e) comb[qsub][lane][e] = o[e];
    comb[qsub][lane][16] = m;
    comb[qsub][lane][17] = l;
  }
  __syncthreads();
  if (kh == 0) {
    float m1 = comb[qsub][lane][16], l1 = comb[qsub][lane][17];
    float M = fmaxf(m, m1);
    float a0 = fast_exp2(m - M), a1 = fast_exp2(m1 - M);
    float L = l * a0 + l1 * a1;
    float inv = L > 0.f ? 1.f / L : 0.f;
    float res[16];
#pragma unroll
    for (int e = 0; e < 16; ++e) res[e] = (o[e] * a0 + comb[qsub][lane][e] * a1) * inv;
    float* op = O + (bt * 1024 + nq) * 64 + h * 16;
    *(float4*)&op[0]  = make_float4(res[0], res[1], res[2], res[3]);
    *(float4*)&op[4]  = make_float4(res[4], res[5], res[6], res[7]);
    *(float4*)&op[8]  = make_float4(res[8], res[9], res[10], res[11]);
    *(float4*)&op[12] = make_float4(res[12], res[13], res[14], res[15]);
  }
}

// ---------------------------------------------------------------- O-proj + residual + LN2
__global__ __launch_bounds__(128) void k_oproj(
    const float* __restrict__ O, const float* __restrict__ x,
    const float* __restrict__ wo, const float* __restrict__ bo,
    const float* __restrict__ g2, const float* __restrict__ be2,
    float* __restrict__ R, float* __restrict__ H2) {
  __shared__ float wlds[64 * 64];
  __shared__ float olds[2][16][68];
  int tid = threadIdx.x, lane = tid & 63, w = tid >> 6;
  for (int i = tid * 4; i < 4096; i += 512)
    *(float4*)&wlds[i] = *(const float4*)&wo[i];
  float bov = bo[lane], g = g2[lane], be = be2[lane];
  __syncthreads();
  int row0 = blockIdx.x * 32 + w * 16;
#pragma unroll
  for (int r = 0; r < 16; ++r) olds[w][r][lane] = O[(row0 + r) * 64 + lane];
  float acc[16];
#pragma unroll
  for (int r = 0; r < 16; ++r) acc[r] = 0.f;
  for (int c = 0; c < 64; c += 4) {
    float wv4[4];
#pragma unroll
    for (int cc = 0; cc < 4; ++cc) wv4[cc] = wlds[(c + cc) * 64 + lane];
#pragma unroll
    for (int r = 0; r < 16; ++r) {
      float4 o4 = *(float4*)&olds[w][r][c];
      acc[r] = fmaf(o4.x, wv4[0], acc[r]); acc[r] = fmaf(o4.y, wv4[1], acc[r]);
      acc[r] = fmaf(o4.z, wv4[2], acc[r]); acc[r] = fmaf(o4.w, wv4[3], acc[r]);
    }
  }
#pragma unroll 1
  for (int r = 0; r < 16; ++r) {
    int row = row0 + r;
    int bt = row >> 10, n = row & 1023;
    int b = bt / Tn, t = bt - b * Tn;
    float xv = x[((b * Nn + n) * Tn + t) * 64 + lane];
    float rv = acc[r] + bov + xv;
    R[row * 64 + lane] = rv;
    float s = rv, s2 = rv * rv;
    wave_reduce2(s, s2);
    float mean = s * 0.015625f;
    float var = s2 * 0.015625f - mean * mean;
    float rs = rsqrtf(var + 1e-5f);
    H2[row * 64 + lane] = (rv - mean) * rs * g + be;
  }
}

// ---------------------------------------------------------------- MLP up + relu
__global__ __launch_bounds__(128) void k_mlp1(
    const float* __restrict__ H2, const float* __restrict__ w1,
    const float* __restrict__ b1, float* __restrict__ U) {
  __shared__ float wlds[64 * 128];
  __shared__ float hlds[2][16][68];
  int tid = threadIdx.x, lane = tid & 63, w = tid >> 6;
  int rb = blockIdx.x >> 1, chf = blockIdx.x & 1;
  for (int i = tid * 4; i < 8192; i += 512) {
    int c = i >> 7, d = i & 127;
    *(float4*)&wlds[i] = *(const float4*)&w1[c * 256 + chf * 128 + d];
  }
  float bv0 = b1[chf * 128 + lane], bv1 = b1[chf * 128 + 64 + lane];
  __syncthreads();
  int row0 = rb * 32 + w * 16;
#pragma unroll
  for (int r = 0; r < 16; ++r) hlds[w][r][lane] = H2[(row0 + r) * 64 + lane];
  float a0[16], a1[16];
#pragma unroll
  for (int r = 0; r < 16; ++r) { a0[r] = 0.f; a1[r] = 0.f; }
  for (int c = 0; c < 64; c += 4) {
    float wA[4], wB[4];
#pragma unroll
    for (int cc = 0; cc < 4; ++cc) {
      wA[cc] = wlds[(c + cc) * 128 + lane];
      wB[cc] = wlds[(c + cc) * 128 + 64 + lane];
    }
#pragma unroll
    for (int r = 0; r < 16; ++r) {
      float4 h4 = *(float4*)&hlds[w][r][c];
      a0[r] = fmaf(h4.x, wA[0], a0[r]); a0[r] = fmaf(h4.y, wA[1], a0[r]);
      a0[r] = fmaf(h4.z, wA[2], a0[r]); a0[r] = fmaf(h4.w, wA[3], a0[r]);
      a1[r] = fmaf(h4.x, wB[0], a1[r]); a1[r] = fmaf(h4.y, wB[1], a1[r]);
      a1[r] = fmaf(h4.z, wB[2], a1[r]); a1[r] = fmaf(h4.w, wB[3], a1[r]);
    }
  }
#pragma unroll 1
  for (int r = 0; r < 16; ++r) {
    int row = row0 + r;
    U[row * 256 + chf * 128 + lane] = fmaxf(a0[r] + bv0, 0.f);
    U[row * 256 + chf * 128 + 64 + lane] = fmaxf(a1[r] + bv1, 0.f);
  }
}

// ---------------------------------------------------------------- MLP down + residual + transpose out
__global__ __launch_bounds__(128) void k_mlp2(
    const float* __restrict__ U, const float* __restrict__ w2,
    const float* __restrict__ b2, const float* __restrict__ R,
    float* __restrict__ out) {
  __shared__ float wlds[64 * 64];
  __shared__ float ulds[2][16][68];
  int tid = threadIdx.x, lane = tid & 63, w = tid >> 6;
  int row0 = blockIdx.x * 32 + w * 16;
  float acc[16];
#pragma unroll
  for (int r = 0; r < 16; ++r) acc[r] = 0.f;
#pragma unroll 1
  for (int ch = 0; ch < 4; ++ch) {
    __syncthreads();
    for (int i = tid * 4; i < 4096; i += 512)
      *(float4*)&wlds[i] = *(const float4*)&w2[ch * 4096 + i];
#pragma unroll
    for (int r = 0; r < 16; ++r)
      ulds[w][r][lane] = U[(row0 + r) * 256 + ch * 64 + lane];
    __syncthreads();
    for (int c = 0; c < 64; c += 4) {
      float wv4[4];
#pragma unroll
      for (int cc = 0; cc < 4; ++cc) wv4[cc] = wlds[(c + cc) * 64 + lane];
#pragma unroll
      for (int r = 0; r < 16; ++r) {
        float4 u4 = *(float4*)&ulds[w][r][c];
        acc[r] = fmaf(u4.x, wv4[0], acc[r]); acc[r] = fmaf(u4.y, wv4[1], acc[r]);
        acc[r] = fmaf(u4.z, wv4[2], acc[r]); acc[r] = fmaf(u4.w, wv4[3], acc[r]);
      }
    }
  }
  float bv = b2[lane];
#pragma unroll 1
  for (int r = 0; r < 16; ++r) {
    int row = row0 + r;
    int bt = row >> 10, n = row & 1023;
    int b = bt / Tn, t = bt - b * Tn;
    out[((b * Nn + n) * Tn + t) * 64 + lane] = acc[r] + bv + R[row * 64 + lane];
  }
}

// ---------------------------------------------------------------- launch
extern "C" void kernel_launch(void* const* d_in, const int* in_sizes, int n_in,
                              void* d_out, int out_size, void* d_ws, size_t ws_size,
                              hipStream_t stream) {
  const float* x   = (const float*)d_in[0];
  const int* adj   = (const int*)d_in[1];
  const float* wq  = (const float*)d_in[2];
  const float* wk  = (const float*)d_in[3];
  const float* wv  = (const float*)d_in[4];
  const float* wo  = (const float*)d_in[5];
  const float* bo  = (const float*)d_in[6];
  const float* w1  = (const float*)d_in[7];
  const float* b1  = (const float*)d_in[8];
  const float* w2  = (const float*)d_in[9];
  const float* b2  = (const float*)d_in[10];
  const float* g1  = (const float*)d_in[11];
  const float* be1 = (const float*)d_in[12];
  const float* g2  = (const float*)d_in[13];
  const float* be2 = (const float*)d_in[14];
  float* out = (float*)d_out;

  float* ws = (float*)d_ws;
  unsigned long long* packed = (unsigned long long*)ws;  // 16384 u64 = 128 KB
  float* Q  = ws + 32768;          // [24*4][1024][16]
  float* K  = Q + 1572864;
  float* V  = K + 1572864;
  float* O  = V + 1572864;         // [24][1024][64] row = bt*1024+n
  float* R  = O + 1572864;
  float* H2 = R + 1572864;
  float* U  = H2 + 1572864;        // [24][1024][256]
  // total ws use: ~63.1 MB

  k_pack<<<4096, 256, 0, stream>>>(adj, packed);
  k_ln1_qkv<<<384, 256, 0, stream>>>(x, wq, wk, wv, g1, be1, Q, K, V);
  k_attn<<<768, 256, 0, stream>>>(Q, K, V, packed, O);
  k_oproj<<<768, 128, 0, stream>>>(O, x, wo, bo, g2, be2, R, H2);
  // 24576 rows / 32 rows-per-block = 768 row-blocks x 2 channel-halves = 1536.
  // (was 768 -> only batch 0 got MLP output: the round-2 absmax 3.88 bug)
  k_mlp1<<<1536, 128, 0, stream>>>(H2, w1, b1, U);
  k_mlp2<<<768, 128, 0, stream>>>(U, w2, b2, R, out);
}

// Round 6
// 231.009 us; speedup vs baseline: 1.5422x; 1.5422x over previous
//
#include <hip/hip_runtime.h>
#include <hip/hip_bf16.h>

#define DEV __device__ __forceinline__

constexpr int Nn = 1024, Tn = 12, Dn = 64;

#if __has_builtin(__builtin_amdgcn_exp2f)
DEV float fast_exp2(float x) { return __builtin_amdgcn_exp2f(x); }
#else
DEV float fast_exp2(float x) { return exp2f(x); }
#endif

typedef __bf16 bf16x8 __attribute__((ext_vector_type(8)));
typedef float f32x4 __attribute__((ext_vector_type(4)));
typedef float f32x16 __attribute__((ext_vector_type(16)));

DEV unsigned f2b(float f) {  // f32 -> bf16 bits (round-half-up)
  unsigned u = __builtin_bit_cast(unsigned, f);
  return (u + 0x8000u) >> 16;
}

DEV void wave_reduce2(float& s, float& s2) {
#pragma unroll
  for (int off = 32; off; off >>= 1) {
    s += __shfl_xor(s, off, 64);
    s2 += __shfl_xor(s2, off, 64);
  }
}

// ---------------------------------------------------------------- pack adj
__global__ __launch_bounds__(256) void k_pack(const int* __restrict__ adj,
                                              unsigned long long* __restrict__ packed) {
  int gw = (blockIdx.x * 256 + threadIdx.x) >> 6;
  int lane = threadIdx.x & 63;
  int v = adj[(gw << 6) + lane];
  unsigned long long m = __ballot(v != 0);
  if (lane == 0) packed[gw] = m;
}

// ---------------------------------------------------------------- LN1 + QKV (bf16 out)
// Outputs: Qb[bth][n][16] (pre-scaled by 0.25*log2e), Kb[bth][n][16], Vt[bth][d][n].
__global__ __launch_bounds__(256) void k_ln1_qkv(
    const float* __restrict__ x, const float* __restrict__ wq,
    const float* __restrict__ wk, const float* __restrict__ wv,
    const float* __restrict__ g1, const float* __restrict__ be1,
    __hip_bfloat16* __restrict__ Qb, __hip_bfloat16* __restrict__ Kb,
    __hip_bfloat16* __restrict__ Vt) {
  __shared__ float wlds[64 * 192];
  __shared__ float hlds[4][16][68];   // wave-private
  int tid = threadIdx.x, lane = tid & 63, w = tid >> 6;
  for (int i = tid * 4; i < 4096; i += 1024) {
    int c = i >> 6, d = i & 63;
    *(float4*)&wlds[c * 192 + d]       = *(const float4*)&wq[i];
    *(float4*)&wlds[c * 192 + 64 + d]  = *(const float4*)&wk[i];
    *(float4*)&wlds[c * 192 + 128 + d] = *(const float4*)&wv[i];
  }
  float g = g1[lane], be = be1[lane];
  __syncthreads();
  int row0 = blockIdx.x * 64 + w * 16;
  int bt = row0 >> 10, n0 = row0 & 1023;
#pragma unroll 1
  for (int r = 0; r < 16; ++r) {
    int n = n0 + r;
    int b = bt / Tn, t = bt - b * Tn;
    float xv = x[((b * Nn + n) * Tn + t) * 64 + lane];
    float s = xv, s2 = xv * xv;
    wave_reduce2(s, s2);
    float mean = s * 0.015625f;
    float var = s2 * 0.015625f - mean * mean;
    float rs = rsqrtf(var + 1e-5f);
    hlds[w][r][lane] = (xv - mean) * rs * g + be;
  }
  float qa[16], ka[16], va[16];
#pragma unroll
  for (int r = 0; r < 16; ++r) { qa[r] = 0.f; ka[r] = 0.f; va[r] = 0.f; }
  for (int c = 0; c < 64; c += 4) {
    float wq4[4], wk4[4], wv4[4];
#pragma unroll
    for (int cc = 0; cc < 4; ++cc) {
      wq4[cc] = wlds[(c + cc) * 192 + lane];
      wk4[cc] = wlds[(c + cc) * 192 + 64 + lane];
      wv4[cc] = wlds[(c + cc) * 192 + 128 + lane];
    }
#pragma unroll
    for (int r = 0; r < 16; ++r) {
      float4 h4 = *(float4*)&hlds[w][r][c];
      qa[r] = fmaf(h4.x, wq4[0], qa[r]); qa[r] = fmaf(h4.y, wq4[1], qa[r]);
      qa[r] = fmaf(h4.z, wq4[2], qa[r]); qa[r] = fmaf(h4.w, wq4[3], qa[r]);
      ka[r] = fmaf(h4.x, wk4[0], ka[r]); ka[r] = fmaf(h4.y, wk4[1], ka[r]);
      ka[r] = fmaf(h4.z, wk4[2], ka[r]); ka[r] = fmaf(h4.w, wk4[3], ka[r]);
      va[r] = fmaf(h4.x, wv4[0], va[r]); va[r] = fmaf(h4.y, wv4[1], va[r]);
      va[r] = fmaf(h4.z, wv4[2], va[r]); va[r] = fmaf(h4.w, wv4[3], va[r]);
    }
  }
  const float QS = 0.25f * 1.44269504088896f;  // 1/sqrt(HD) * log2(e)
  int hh = lane >> 4, cc = lane & 15;
#pragma unroll 1
  for (int r = 0; r < 16; ++r) {
    int n = n0 + r;
    size_t idx = ((size_t)(bt * 4 + hh) * 1024 + n) * 16 + cc;
    Qb[idx] = __hip_bfloat16_raw{(unsigned short)f2b(qa[r] * QS)};
    Kb[idx] = __hip_bfloat16_raw{(unsigned short)f2b(ka[r])};
  }
  // V transpose via LDS (hlds no longer needed): Vt[bth][d][n]
#pragma unroll
  for (int r = 0; r < 16; ++r) hlds[w][r][lane] = va[r];
  unsigned os[8];
#pragma unroll
  for (int j = 0; j < 8; ++j)
    os[j] = f2b(hlds[w][2 * j][lane]) | (f2b(hlds[w][2 * j + 1][lane]) << 16);
  uint4* vo = (uint4*)(Vt + ((size_t)(bt * 4 + hh) * 16 + cc) * 1024 + n0);
  vo[0] = make_uint4(os[0], os[1], os[2], os[3]);
  vo[1] = make_uint4(os[4], os[5], os[6], os[7]);
}

// ---------------------------------------------------------------- attention (MFMA)
// Wave owns 32 queries. Per 32-key tile:
//   S^T = mfma_32x32x16(A=K-tile, B=Q^T)  -> lane holds q=lane&31, 16 keys
//   lane-local online softmax (+1 shfl_xor(32) for tile max / final l)
//   P^T -> bf16 -> LDS (80B rows) -> B-frags -> O^T += mfma_16x16x32(V^T, P^T) x2
// Frags read straight from global (K/V/Q are L2-resident bf16).
__global__ __launch_bounds__(256) void k_attn(
    const __hip_bfloat16* __restrict__ Qb, const __hip_bfloat16* __restrict__ Kb,
    const __hip_bfloat16* __restrict__ Vt, const unsigned* __restrict__ packed32,
    float* __restrict__ O) {
  __shared__ uint4 smem[4][160];  // 2560 B per wave: P bounce, then O transpose
  int bid = (blockIdx.x & 7) * 96 + (blockIdx.x >> 3);  // XCD-chunked (768%8==0)
  int bth = bid >> 3, qb = bid & 7;
  int bt = bth >> 2, h = bth & 3;
  int tid = threadIdx.x, lane = tid & 63, w = tid >> 6;
  int l15 = lane & 15, l31 = lane & 31, hi = lane >> 5, g4 = lane >> 4;
  int q0 = qb * 128 + w * 32;
  // Q^T B-frag: col q=l31, k(d)=hi*8+j  (one 16B load, reused all tiles)
  bf16x8 qfrag = __builtin_bit_cast(bf16x8,
      *(const uint4*)(Qb + ((size_t)bth * 1024 + q0 + l31) * 16 + hi * 8));
  const uint4* kbase = (const uint4*)(Kb + (size_t)bth * 1024 * 16);  // 2 uint4/key
  const uint4* vtb = (const uint4*)(Vt + (size_t)bth * 16 * 1024);    // 128 uint4/d-row
  const unsigned* mbase = packed32 + (size_t)(q0 + l31) * 32;
  char* myp = (char*)&smem[w][0];

  f32x4 o1 = {0.f, 0.f, 0.f, 0.f}, o2 = {0.f, 0.f, 0.f, 0.f};
  float m = -1e38f, lsum = 0.f;
  uint4 kf = kbase[l31 * 2 + hi];
  uint4 vf = vtb[l15 * 128 + g4];
  unsigned mk = mbase[0];
#pragma unroll 1
  for (int kt = 0; kt < 32; ++kt) {
    int ktn = kt < 31 ? kt + 1 : 31;  // clamped prefetch
    uint4 kf_n = kbase[ktn * 64 + l31 * 2 + hi];
    uint4 vf_n = vtb[l15 * 128 + ktn * 4 + g4];
    unsigned mk_n = mbase[ktn];
    f32x16 s = {0.f,0.f,0.f,0.f, 0.f,0.f,0.f,0.f, 0.f,0.f,0.f,0.f, 0.f,0.f,0.f,0.f};
    s = __builtin_amdgcn_mfma_f32_32x32x16_bf16(
        __builtin_bit_cast(bf16x8, kf), qfrag, s, 0, 0, 0);
    // mask: S^T row (key) = (r&3)+8*(r>>2)+4*hi, col q = l31
    unsigned mm = mk >> (hi * 4);
#pragma unroll
    for (int r = 0; r < 16; ++r)
      if (!((mm >> ((r & 3) + 8 * (r >> 2))) & 1u)) s[r] = -3e38f;
    float tm = s[0];
#pragma unroll
    for (int r = 1; r < 16; ++r) tm = fmaxf(tm, s[r]);
    tm = fmaxf(tm, __shfl_xor(tm, 32));
    float mn = fmaxf(m, tm);
    float sc = fast_exp2(m - mn);
    m = mn;
    lsum *= sc;
    float sc1 = __shfl(sc, l15), sc2 = __shfl(sc, l15 + 16);  // O regs are q=l15(+16)
#pragma unroll
    for (int r = 0; r < 4; ++r) { o1[r] *= sc1; o2[r] *= sc2; }
    float p[16];
#pragma unroll
    for (int r = 0; r < 16; ++r) { p[r] = fast_exp2(s[r] - m); lsum += p[r]; }
    unsigned pw[8];
#pragma unroll
    for (int j = 0; j < 8; ++j) pw[j] = f2b(p[2 * j]) | (f2b(p[2 * j + 1]) << 16);
    // P rows 80 B (2-way banks): bytes 0..63 = keys 0..31 in order
    char* wp = myp + l31 * 80 + hi * 8;
    *(uint2*)(wp +  0) = make_uint2(pw[0], pw[1]);
    *(uint2*)(wp + 16) = make_uint2(pw[2], pw[3]);
    *(uint2*)(wp + 32) = make_uint2(pw[4], pw[5]);
    *(uint2*)(wp + 48) = make_uint2(pw[6], pw[7]);
    uint4 b1 = *(uint4*)(myp + l15 * 80 + g4 * 16);
    uint4 b2 = *(uint4*)(myp + (l15 + 16) * 80 + g4 * 16);
    bf16x8 vfrag = __builtin_bit_cast(bf16x8, vf);
    o1 = __builtin_amdgcn_mfma_f32_16x16x32_bf16(
        vfrag, __builtin_bit_cast(bf16x8, b1), o1, 0, 0, 0);
    o2 = __builtin_amdgcn_mfma_f32_16x16x32_bf16(
        vfrag, __builtin_bit_cast(bf16x8, b2), o2, 0, 0, 0);
    kf = kf_n; vf = vf_n; mk = mk_n;
  }
  float lt = lsum + __shfl_xor(lsum, 32);
  float inv = lt > 0.f ? 1.f / lt : 0.f;
  float inv1 = __shfl(inv, l15), inv2 = __shfl(inv, l15 + 16);
  // O^T -> LDS (20-float rows) -> coalesced global: O[row][64] at ch h*16+d
  float* of = (float*)myp;
#pragma unroll
  for (int r = 0; r < 4; ++r) {
    of[l15 * 20 + g4 * 4 + r] = o1[r] * inv1;
    of[(l15 + 16) * 20 + g4 * 4 + r] = o2[r] * inv2;
  }
  float* orow = O + ((size_t)bt * 1024 + q0 + l31) * 64 + h * 16 + hi * 8;
  *(float4*)(orow)     = *(float4*)(myp + l31 * 80 + hi * 32);
  *(float4*)(orow + 4) = *(float4*)(myp + l31 * 80 + hi * 32 + 16);
}

// ---------------------------------------------------------------- O-proj + residual + LN2
__global__ __launch_bounds__(256) void k_oproj(
    const float* __restrict__ O, const float* __restrict__ x,
    const float* __restrict__ wo, const float* __restrict__ bo,
    const float* __restrict__ g2, const float* __restrict__ be2,
    float* __restrict__ R, float* __restrict__ H2) {
  __shared__ float wlds[64 * 64];
  __shared__ float olds[4][16][68];
  int tid = threadIdx.x, lane = tid & 63, w = tid >> 6;
  for (int i = tid * 4; i < 4096; i += 1024)
    *(float4*)&wlds[i] = *(const float4*)&wo[i];
  float bov = bo[lane], g = g2[lane], be = be2[lane];
  __syncthreads();
  int row0 = blockIdx.x * 64 + w * 16;
#pragma unroll
  for (int r = 0; r < 16; ++r) olds[w][r][lane] = O[(size_t)(row0 + r) * 64 + lane];
  float acc[16];
#pragma unroll
  for (int r = 0; r < 16; ++r) acc[r] = 0.f;
  for (int c = 0; c < 64; c += 4) {
    float wv4[4];
#pragma unroll
    for (int cc = 0; cc < 4; ++cc) wv4[cc] = wlds[(c + cc) * 64 + lane];
#pragma unroll
    for (int r = 0; r < 16; ++r) {
      float4 o4 = *(float4*)&olds[w][r][c];
      acc[r] = fmaf(o4.x, wv4[0], acc[r]); acc[r] = fmaf(o4.y, wv4[1], acc[r]);
      acc[r] = fmaf(o4.z, wv4[2], acc[r]); acc[r] = fmaf(o4.w, wv4[3], acc[r]);
    }
  }
#pragma unroll 1
  for (int r = 0; r < 16; ++r) {
    int row = row0 + r;
    int bt = row >> 10, n = row & 1023;
    int b = bt / Tn, t = bt - b * Tn;
    float xv = x[((b * Nn + n) * Tn + t) * 64 + lane];
    float rv = acc[r] + bov + xv;
    R[(size_t)row * 64 + lane] = rv;
    float s = rv, s2 = rv * rv;
    wave_reduce2(s, s2);
    float mean = s * 0.015625f;
    float var = s2 * 0.015625f - mean * mean;
    float rs = rsqrtf(var + 1e-5f);
    H2[(size_t)row * 64 + lane] = (rv - mean) * rs * g + be;
  }
}

// ---------------------------------------------------------------- MLP up + relu
__global__ __launch_bounds__(256) void k_mlp1(
    const float* __restrict__ H2, const float* __restrict__ w1,
    const float* __restrict__ b1, float* __restrict__ U) {
  __shared__ float wlds[64 * 128];
  __shared__ float hlds[4][16][68];
  int tid = threadIdx.x, lane = tid & 63, w = tid >> 6;
  int rb = blockIdx.x >> 1, chf = blockIdx.x & 1;
  for (int i = tid * 4; i < 8192; i += 1024) {
    int c = i >> 7, d = i & 127;
    *(float4*)&wlds[i] = *(const float4*)&w1[c * 256 + chf * 128 + d];
  }
  float bv0 = b1[chf * 128 + lane], bv1 = b1[chf * 128 + 64 + lane];
  __syncthreads();
  int row0 = rb * 64 + w * 16;
#pragma unroll
  for (int r = 0; r < 16; ++r) hlds[w][r][lane] = H2[(size_t)(row0 + r) * 64 + lane];
  float a0[16], a1[16];
#pragma unroll
  for (int r = 0; r < 16; ++r) { a0[r] = 0.f; a1[r] = 0.f; }
  for (int c = 0; c < 64; c += 4) {
    float wA[4], wB[4];
#pragma unroll
    for (int cc = 0; cc < 4; ++cc) {
      wA[cc] = wlds[(c + cc) * 128 + lane];
      wB[cc] = wlds[(c + cc) * 128 + 64 + lane];
    }
#pragma unroll
    for (int r = 0; r < 16; ++r) {
      float4 h4 = *(float4*)&hlds[w][r][c];
      a0[r] = fmaf(h4.x, wA[0], a0[r]); a0[r] = fmaf(h4.y, wA[1], a0[r]);
      a0[r] = fmaf(h4.z, wA[2], a0[r]); a0[r] = fmaf(h4.w, wA[3], a0[r]);
      a1[r] = fmaf(h4.x, wB[0], a1[r]); a1[r] = fmaf(h4.y, wB[1], a1[r]);
      a1[r] = fmaf(h4.z, wB[2], a1[r]); a1[r] = fmaf(h4.w, wB[3], a1[r]);
    }
  }
#pragma unroll 1
  for (int r = 0; r < 16; ++r) {
    size_t row = row0 + r;
    U[row * 256 + chf * 128 + lane] = fmaxf(a0[r] + bv0, 0.f);
    U[row * 256 + chf * 128 + 64 + lane] = fmaxf(a1[r] + bv1, 0.f);
  }
}

// ---------------------------------------------------------------- MLP down + residual + transpose out
__global__ __launch_bounds__(256) void k_mlp2(
    const float* __restrict__ U, const float* __restrict__ w2,
    const float* __restrict__ b2, const float* __restrict__ R,
    float* __restrict__ out) {
  __shared__ float wlds[64 * 64];
  __shared__ float ulds[4][16][68];
  int tid = threadIdx.x, lane = tid & 63, w = tid >> 6;
  int row0 = blockIdx.x * 64 + w * 16;
  float acc[16];
#pragma unroll
  for (int r = 0; r < 16; ++r) acc[r] = 0.f;
#pragma unroll 1
  for (int ch = 0; ch < 4; ++ch) {
    __syncthreads();
    for (int i = tid * 4; i < 4096; i += 1024)
      *(float4*)&wlds[i] = *(const float4*)&w2[ch * 4096 + i];
#pragma unroll
    for (int r = 0; r < 16; ++r)
      ulds[w][r][lane] = U[(size_t)(row0 + r) * 256 + ch * 64 + lane];
    __syncthreads();
    for (int c = 0; c < 64; c += 4) {
      float wv4[4];
#pragma unroll
      for (int cc = 0; cc < 4; ++cc) wv4[cc] = wlds[(c + cc) * 64 + lane];
#pragma unroll
      for (int r = 0; r < 16; ++r) {
        float4 u4 = *(float4*)&ulds[w][r][c];
        acc[r] = fmaf(u4.x, wv4[0], acc[r]); acc[r] = fmaf(u4.y, wv4[1], acc[r]);
        acc[r] = fmaf(u4.z, wv4[2], acc[r]); acc[r] = fmaf(u4.w, wv4[3], acc[r]);
      }
    }
  }
  float bv = b2[lane];
#pragma unroll 1
  for (int r = 0; r < 16; ++r) {
    int row = row0 + r;
    int bt = row >> 10, n = row & 1023;
    int b = bt / Tn, t = bt - b * Tn;
    out[((size_t)(b * Nn + n) * Tn + t) * 64 + lane] = acc[r] + bv + R[(size_t)row * 64 + lane];
  }
}

// ---------------------------------------------------------------- launch
extern "C" void kernel_launch(void* const* d_in, const int* in_sizes, int n_in,
                              void* d_out, int out_size, void* d_ws, size_t ws_size,
                              hipStream_t stream) {
  const float* x   = (const float*)d_in[0];
  const int* adj   = (const int*)d_in[1];
  const float* wq  = (const float*)d_in[2];
  const float* wk  = (const float*)d_in[3];
  const float* wv  = (const float*)d_in[4];
  const float* wo  = (const float*)d_in[5];
  const float* bo  = (const float*)d_in[6];
  const float* w1  = (const float*)d_in[7];
  const float* b1  = (const float*)d_in[8];
  const float* w2  = (const float*)d_in[9];
  const float* b2  = (const float*)d_in[10];
  const float* g1  = (const float*)d_in[11];
  const float* be1 = (const float*)d_in[12];
  const float* g2  = (const float*)d_in[13];
  const float* be2 = (const float*)d_in[14];
  float* out = (float*)d_out;

  float* ws = (float*)d_ws;
  unsigned long long* packed = (unsigned long long*)ws;        // 128 KB
  __hip_bfloat16* Qb = (__hip_bfloat16*)(ws + 32768);          // 3 MB each
  __hip_bfloat16* Kb = (__hip_bfloat16*)(ws + 819200);
  __hip_bfloat16* Vt = (__hip_bfloat16*)(ws + 1605632);
  float* O  = ws + 2392064;   // [24576][64]
  float* R  = ws + 3964928;
  float* H2 = ws + 5537792;
  float* U  = ws + 7110656;   // [24576][256]; end 13402112 floats = 53.6 MB

  k_pack<<<4096, 256, 0, stream>>>(adj, packed);
  k_ln1_qkv<<<384, 256, 0, stream>>>(x, wq, wk, wv, g1, be1, Qb, Kb, Vt);
  k_attn<<<768, 256, 0, stream>>>(Qb, Kb, Vt, (const unsigned*)packed, O);
  k_oproj<<<384, 256, 0, stream>>>(O, x, wo, bo, g2, be2, R, H2);
  k_mlp1<<<768, 256, 0, stream>>>(H2, w1, b1, U);
  k_mlp2<<<384, 256, 0, stream>>>(U, w2, b2, R, out);
}

// Round 8
// 180.323 us; speedup vs baseline: 1.9757x; 1.2811x over previous
//
#include <hip/hip_runtime.h>
#include <hip/hip_bf16.h>

#define DEV __device__ __forceinline__

constexpr int Nn = 1024, Tn = 12, Dn = 64;

#if __has_builtin(__builtin_amdgcn_exp2f)
DEV float fast_exp2(float x) { return __builtin_amdgcn_exp2f(x); }
#else
DEV float fast_exp2(float x) { return exp2f(x); }
#endif

typedef __bf16 bf16x8 __attribute__((ext_vector_type(8)));
typedef float f32x4 __attribute__((ext_vector_type(4)));
typedef float f32x16 __attribute__((ext_vector_type(16)));

#define Z16 {0.f,0.f,0.f,0.f, 0.f,0.f,0.f,0.f, 0.f,0.f,0.f,0.f, 0.f,0.f,0.f,0.f}

DEV unsigned f2b(float f) {  // f32 -> bf16 bits (round-half-up)
  unsigned u = __builtin_bit_cast(unsigned, f);
  return (u + 0x8000u) >> 16;
}
DEV unsigned pk2(float a, float b) { return f2b(a) | (f2b(b) << 16); }
DEV float b2f(unsigned hbits) { return __builtin_bit_cast(float, hbits << 16); }
// split pair into hi word + lo word (two-term bf16 representation)
DEV void split2(float a, float b, unsigned& hw, unsigned& lw) {
  unsigned ha = f2b(a), hb = f2b(b);
  hw = ha | (hb << 16);
  lw = pk2(a - b2f(ha), b - b2f(hb));
}

DEV void wave_reduce2(float& s, float& s2) {
#pragma unroll
  for (int off = 32; off; off >>= 1) {
    s += __shfl_xor(s, off, 64);
    s2 += __shfl_xor(s2, off, 64);
  }
}

// ---------------------------------------------------------------- pack adj
__global__ __launch_bounds__(256) void k_pack(const int* __restrict__ adj,
                                              unsigned long long* __restrict__ packed) {
  int gw = (blockIdx.x * 256 + threadIdx.x) >> 6;
  int lane = threadIdx.x & 63;
  int v = adj[(gw << 6) + lane];
  unsigned long long m = __ballot(v != 0);
  if (lane == 0) packed[gw] = m;
}

// ---------------------------------------------------------------- prep: frag-pack weights, hi+lo
// woP: groups [0,8) hi, [8,16) lo.  w1P: [0,32) hi, [32,64) lo (g2 folded).
// w2P: [0,32) hi, [32,64) lo.  b1p = b1 + be2@w1 (fp32).
__global__ __launch_bounds__(256) void k_prep(
    const float* __restrict__ wo, const float* __restrict__ w1,
    const float* __restrict__ w2, const float* __restrict__ b1,
    const float* __restrict__ g2, const float* __restrict__ be2,
    __hip_bfloat16* __restrict__ woP, __hip_bfloat16* __restrict__ w1P,
    __hip_bfloat16* __restrict__ w2P, float* __restrict__ b1p) {
  int tid = blockIdx.x * 256 + threadIdx.x;
  if (tid < 512) {                       // woP: 8 frag-groups x 64 lanes
    int fg = tid >> 6, lane = tid & 63;
    int t = fg >> 2, ks = fg & 3, hi = lane >> 5, l31 = lane & 31;
    unsigned hw[4], lw[4];
#pragma unroll
    for (int jj = 0; jj < 4; ++jj) {
      int k = ks * 16 + hi * 8 + jj * 2;
      split2(wo[k * 64 + t * 32 + l31], wo[(k + 1) * 64 + t * 32 + l31], hw[jj], lw[jj]);
    }
    *(uint4*)(woP + (size_t)tid * 8) = make_uint4(hw[0], hw[1], hw[2], hw[3]);
    *(uint4*)(woP + (size_t)(512 + tid) * 8) = make_uint4(lw[0], lw[1], lw[2], lw[3]);
  } else if (tid < 2560) {               // w1P: 32 frag-groups
    int id = tid - 512;
    int fg = id >> 6, lane = id & 63;
    int tile = fg >> 2, ks = fg & 3, hi = lane >> 5, l31 = lane & 31;
    unsigned hw[4], lw[4];
#pragma unroll
    for (int jj = 0; jj < 4; ++jj) {
      int k = ks * 16 + hi * 8 + jj * 2;
      split2(g2[k] * w1[k * 256 + tile * 32 + l31],
             g2[k + 1] * w1[(k + 1) * 256 + tile * 32 + l31], hw[jj], lw[jj]);
    }
    *(uint4*)(w1P + (size_t)id * 8) = make_uint4(hw[0], hw[1], hw[2], hw[3]);
    *(uint4*)(w1P + (size_t)(2048 + id) * 8) = make_uint4(lw[0], lw[1], lw[2], lw[3]);
  } else if (tid < 4608) {               // w2P: 32 frag-groups
    int id = tid - 2560;
    int fg = id >> 6, lane = id & 63;
    int t = fg >> 4, ks = fg & 15, hi = lane >> 5, l31 = lane & 31;
    unsigned hw[4], lw[4];
#pragma unroll
    for (int jj = 0; jj < 4; ++jj) {
      int k = ks * 16 + hi * 8 + jj * 2;
      split2(w2[k * 64 + t * 32 + l31], w2[(k + 1) * 64 + t * 32 + l31], hw[jj], lw[jj]);
    }
    *(uint4*)(w2P + (size_t)id * 8) = make_uint4(hw[0], hw[1], hw[2], hw[3]);
    *(uint4*)(w2P + (size_t)(2048 + id) * 8) = make_uint4(lw[0], lw[1], lw[2], lw[3]);
  } else if (tid < 4864) {               // b1p
    int o = tid - 4608;
    float s = b1[o];
    for (int c = 0; c < 64; ++c) s += be2[c] * w1[c * 256 + o];
    b1p[o] = s;
  }
}

// ---------------------------------------------------------------- LN1 + QKV (bf16 out) [unchanged]
__global__ __launch_bounds__(256) void k_ln1_qkv(
    const float* __restrict__ x, const float* __restrict__ wq,
    const float* __restrict__ wk, const float* __restrict__ wv,
    const float* __restrict__ g1, const float* __restrict__ be1,
    __hip_bfloat16* __restrict__ Qb, __hip_bfloat16* __restrict__ Kb,
    __hip_bfloat16* __restrict__ Vt) {
  __shared__ float wlds[64 * 192];
  __shared__ float hlds[4][16][68];   // wave-private
  int tid = threadIdx.x, lane = tid & 63, w = tid >> 6;
  for (int i = tid * 4; i < 4096; i += 1024) {
    int c = i >> 6, d = i & 63;
    *(float4*)&wlds[c * 192 + d]       = *(const float4*)&wq[i];
    *(float4*)&wlds[c * 192 + 64 + d]  = *(const float4*)&wk[i];
    *(float4*)&wlds[c * 192 + 128 + d] = *(const float4*)&wv[i];
  }
  float g = g1[lane], be = be1[lane];
  __syncthreads();
  int row0 = blockIdx.x * 64 + w * 16;
  int bt = row0 >> 10, n0 = row0 & 1023;
#pragma unroll 1
  for (int r = 0; r < 16; ++r) {
    int n = n0 + r;
    int b = bt / Tn, t = bt - b * Tn;
    float xv = x[((b * Nn + n) * Tn + t) * 64 + lane];
    float s = xv, s2 = xv * xv;
    wave_reduce2(s, s2);
    float mean = s * 0.015625f;
    float var = s2 * 0.015625f - mean * mean;
    float rs = rsqrtf(var + 1e-5f);
    hlds[w][r][lane] = (xv - mean) * rs * g + be;
  }
  float qa[16], ka[16], va[16];
#pragma unroll
  for (int r = 0; r < 16; ++r) { qa[r] = 0.f; ka[r] = 0.f; va[r] = 0.f; }
  for (int c = 0; c < 64; c += 4) {
    float wq4[4], wk4[4], wv4[4];
#pragma unroll
    for (int cc = 0; cc < 4; ++cc) {
      wq4[cc] = wlds[(c + cc) * 192 + lane];
      wk4[cc] = wlds[(c + cc) * 192 + 64 + lane];
      wv4[cc] = wlds[(c + cc) * 192 + 128 + lane];
    }
#pragma unroll
    for (int r = 0; r < 16; ++r) {
      float4 h4 = *(float4*)&hlds[w][r][c];
      qa[r] = fmaf(h4.x, wq4[0], qa[r]); qa[r] = fmaf(h4.y, wq4[1], qa[r]);
      qa[r] = fmaf(h4.z, wq4[2], qa[r]); qa[r] = fmaf(h4.w, wq4[3], qa[r]);
      ka[r] = fmaf(h4.x, wk4[0], ka[r]); ka[r] = fmaf(h4.y, wk4[1], ka[r]);
      ka[r] = fmaf(h4.z, wk4[2], ka[r]); ka[r] = fmaf(h4.w, wk4[3], ka[r]);
      va[r] = fmaf(h4.x, wv4[0], va[r]); va[r] = fmaf(h4.y, wv4[1], va[r]);
      va[r] = fmaf(h4.z, wv4[2], va[r]); va[r] = fmaf(h4.w, wv4[3], va[r]);
    }
  }
  const float QS = 0.25f * 1.44269504088896f;  // 1/sqrt(HD) * log2(e)
  int hh = lane >> 4, cc = lane & 15;
#pragma unroll 1
  for (int r = 0; r < 16; ++r) {
    int n = n0 + r;
    size_t idx = ((size_t)(bt * 4 + hh) * 1024 + n) * 16 + cc;
    Qb[idx] = __hip_bfloat16_raw{(unsigned short)f2b(qa[r] * QS)};
    Kb[idx] = __hip_bfloat16_raw{(unsigned short)f2b(ka[r])};
  }
#pragma unroll
  for (int r = 0; r < 16; ++r) hlds[w][r][lane] = va[r];
  unsigned os[8];
#pragma unroll
  for (int j = 0; j < 8; ++j)
    os[j] = f2b(hlds[w][2 * j][lane]) | (f2b(hlds[w][2 * j + 1][lane]) << 16);
  uint4* vo = (uint4*)(Vt + ((size_t)(bt * 4 + hh) * 16 + cc) * 1024 + n0);
  vo[0] = make_uint4(os[0], os[1], os[2], os[3]);
  vo[1] = make_uint4(os[4], os[5], os[6], os[7]);
}

// ---------------------------------------------------------------- attention (MFMA) [unchanged]
__global__ __launch_bounds__(256) void k_attn(
    const __hip_bfloat16* __restrict__ Qb, const __hip_bfloat16* __restrict__ Kb,
    const __hip_bfloat16* __restrict__ Vt, const unsigned* __restrict__ packed32,
    float* __restrict__ O) {
  __shared__ uint4 smem[4][160];
  int bid = (blockIdx.x & 7) * 96 + (blockIdx.x >> 3);  // XCD-chunked (768%8==0)
  int bth = bid >> 3, qb = bid & 7;
  int bt = bth >> 2, h = bth & 3;
  int tid = threadIdx.x, lane = tid & 63, w = tid >> 6;
  int l15 = lane & 15, l31 = lane & 31, hi = lane >> 5, g4 = lane >> 4;
  int q0 = qb * 128 + w * 32;
  bf16x8 qfrag = __builtin_bit_cast(bf16x8,
      *(const uint4*)(Qb + ((size_t)bth * 1024 + q0 + l31) * 16 + hi * 8));
  const uint4* kbase = (const uint4*)(Kb + (size_t)bth * 1024 * 16);
  const uint4* vtb = (const uint4*)(Vt + (size_t)bth * 16 * 1024);
  const unsigned* mbase = packed32 + (size_t)(q0 + l31) * 32;
  char* myp = (char*)&smem[w][0];

  f32x4 o1 = {0.f, 0.f, 0.f, 0.f}, o2 = {0.f, 0.f, 0.f, 0.f};
  float m = -1e38f, lsum = 0.f;
  uint4 kf = kbase[l31 * 2 + hi];
  uint4 vf = vtb[l15 * 128 + g4];
  unsigned mk = mbase[0];
#pragma unroll 1
  for (int kt = 0; kt < 32; ++kt) {
    int ktn = kt < 31 ? kt + 1 : 31;
    uint4 kf_n = kbase[ktn * 64 + l31 * 2 + hi];
    uint4 vf_n = vtb[l15 * 128 + ktn * 4 + g4];
    unsigned mk_n = mbase[ktn];
    f32x16 s = Z16;
    s = __builtin_amdgcn_mfma_f32_32x32x16_bf16(
        __builtin_bit_cast(bf16x8, kf), qfrag, s, 0, 0, 0);
    unsigned mm = mk >> (hi * 4);
#pragma unroll
    for (int r = 0; r < 16; ++r)
      if (!((mm >> ((r & 3) + 8 * (r >> 2))) & 1u)) s[r] = -3e38f;
    float tm = s[0];
#pragma unroll
    for (int r = 1; r < 16; ++r) tm = fmaxf(tm, s[r]);
    tm = fmaxf(tm, __shfl_xor(tm, 32));
    float mn = fmaxf(m, tm);
    float sc = fast_exp2(m - mn);
    m = mn;
    lsum *= sc;
    float sc1 = __shfl(sc, l15), sc2 = __shfl(sc, l15 + 16);
#pragma unroll
    for (int r = 0; r < 4; ++r) { o1[r] *= sc1; o2[r] *= sc2; }
    float p[16];
#pragma unroll
    for (int r = 0; r < 16; ++r) { p[r] = fast_exp2(s[r] - m); lsum += p[r]; }
    unsigned pw[8];
#pragma unroll
    for (int j = 0; j < 8; ++j) pw[j] = pk2(p[2 * j], p[2 * j + 1]);
    char* wp = myp + l31 * 80 + hi * 8;
    *(uint2*)(wp +  0) = make_uint2(pw[0], pw[1]);
    *(uint2*)(wp + 16) = make_uint2(pw[2], pw[3]);
    *(uint2*)(wp + 32) = make_uint2(pw[4], pw[5]);
    *(uint2*)(wp + 48) = make_uint2(pw[6], pw[7]);
    uint4 b1v = *(uint4*)(myp + l15 * 80 + g4 * 16);
    uint4 b2v = *(uint4*)(myp + (l15 + 16) * 80 + g4 * 16);
    bf16x8 vfrag = __builtin_bit_cast(bf16x8, vf);
    o1 = __builtin_amdgcn_mfma_f32_16x16x32_bf16(
        vfrag, __builtin_bit_cast(bf16x8, b1v), o1, 0, 0, 0);
    o2 = __builtin_amdgcn_mfma_f32_16x16x32_bf16(
        vfrag, __builtin_bit_cast(bf16x8, b2v), o2, 0, 0, 0);
    kf = kf_n; vf = vf_n; mk = mk_n;
  }
  float lt = lsum + __shfl_xor(lsum, 32);
  float inv = lt > 0.f ? 1.f / lt : 0.f;
  float inv1 = __shfl(inv, l15), inv2 = __shfl(inv, l15 + 16);
  float* of = (float*)myp;
#pragma unroll
  for (int r = 0; r < 4; ++r) {
    of[l15 * 20 + g4 * 4 + r] = o1[r] * inv1;
    of[(l15 + 16) * 20 + g4 * 4 + r] = o2[r] * inv2;
  }
  float* orow = O + ((size_t)bt * 1024 + q0 + l31) * 64 + h * 16 + hi * 8;
  *(float4*)(orow)     = *(float4*)(myp + l31 * 80 + hi * 32);
  *(float4*)(orow + 4) = *(float4*)(myp + l31 * 80 + hi * 32 + 16);
}

// ---------------------------------------------------------------- fused tail (split-bf16 MFMA)
// Same dataflow as round 7, but every GEMM uses two-term bf16 (hi+lo) on both
// weights and activations: D = Wh*Xh + Wh*Xl + Wl*Xh  (near-fp32 precision).
// 1 wave per block (768 blocks) so all CUs are covered.
__global__ __launch_bounds__(64) void k_tail(
    const float* __restrict__ O, const float* __restrict__ x,
    const __hip_bfloat16* __restrict__ woP, const __hip_bfloat16* __restrict__ w1P,
    const __hip_bfloat16* __restrict__ w2P, const float* __restrict__ bo,
    const float* __restrict__ b1p, const float* __restrict__ b2,
    float* __restrict__ out) {
  __shared__ float bias[384];     // [0,64) bo, [64,128) b2, [128,384) b1p
  __shared__ char wbuf[13312];    // [0,8704) H2 hi/lo rows 272B (epilogue overlays), [8704,..) U rows 144B
  int lane = threadIdx.x & 63;
  int l31 = lane & 31, hi = lane >> 5;
  for (int i = threadIdx.x; i < 384; i += 64)
    bias[i] = i < 64 ? bo[i] : (i < 128 ? b2[i - 64] : b1p[i - 128]);
  __syncthreads();

  int tok = blockIdx.x * 32 + l31;
  int bt = tok >> 10, n = tok & 1023;
  int b = bt / Tn, tt_time = bt - b * Tn;
  const float* orow = O + (size_t)tok * 64;
  const float* xrow = x + ((size_t)(b * Nn + n) * Tn + tt_time) * 64;
  char* h2b = wbuf;
  char* pub = wbuf + 8704;

#define LDA(base, g) __builtin_bit_cast(bf16x8, *(const uint4*)((base) + ((size_t)(g) * 64 + lane) * 8))
#define MF(A, B, C) __builtin_amdgcn_mfma_f32_32x32x16_bf16(A, B, C, 0, 0, 0)

  // ---- GEMM1: d1 = wo^T * O^T  (split O and wo)
  bf16x8 ofh[4], ofl[4];
#pragma unroll
  for (int ks = 0; ks < 4; ++ks) {
    float4 oa = *(const float4*)(orow + ks * 16 + hi * 8);
    float4 ob = *(const float4*)(orow + ks * 16 + hi * 8 + 4);
    unsigned hw[4], lw[4];
    split2(oa.x, oa.y, hw[0], lw[0]); split2(oa.z, oa.w, hw[1], lw[1]);
    split2(ob.x, ob.y, hw[2], lw[2]); split2(ob.z, ob.w, hw[3], lw[3]);
    ofh[ks] = __builtin_bit_cast(bf16x8, make_uint4(hw[0], hw[1], hw[2], hw[3]));
    ofl[ks] = __builtin_bit_cast(bf16x8, make_uint4(lw[0], lw[1], lw[2], lw[3]));
  }
  f32x16 d1a = Z16, d1b = Z16;
#pragma unroll
  for (int ks = 0; ks < 4; ++ks) {
    bf16x8 wha = LDA(woP, ks), wla = LDA(woP, 8 + ks);
    d1a = MF(wha, ofh[ks], d1a); d1a = MF(wha, ofl[ks], d1a); d1a = MF(wla, ofh[ks], d1a);
    bf16x8 whb = LDA(woP, 4 + ks), wlb = LDA(woP, 12 + ks);
    d1b = MF(whb, ofh[ks], d1b); d1b = MF(whb, ofl[ks], d1b); d1b = MF(wlb, ofh[ks], d1b);
  }
  // ---- + bo + x  (ch = rq*8 + hi*4 + i  [+32 for d1b])
#pragma unroll
  for (int rq = 0; rq < 4; ++rq) {
    float4 xa = *(const float4*)(xrow + rq * 8 + hi * 4);
    float4 xb = *(const float4*)(xrow + 32 + rq * 8 + hi * 4);
    int ca = rq * 8 + hi * 4, cb = 32 + rq * 8 + hi * 4;
    d1a[rq * 4 + 0] += bias[ca + 0] + xa.x;  d1a[rq * 4 + 1] += bias[ca + 1] + xa.y;
    d1a[rq * 4 + 2] += bias[ca + 2] + xa.z;  d1a[rq * 4 + 3] += bias[ca + 3] + xa.w;
    d1b[rq * 4 + 0] += bias[cb + 0] + xb.x;  d1b[rq * 4 + 1] += bias[cb + 1] + xb.y;
    d1b[rq * 4 + 2] += bias[cb + 2] + xb.z;  d1b[rq * 4 + 3] += bias[cb + 3] + xb.w;
  }
  // ---- LN2 (gamma/beta folded into w1P/b1p): lane-local + 1 shfl
  float s = 0.f, s2 = 0.f;
#pragma unroll
  for (int r = 0; r < 16; ++r) {
    s += d1a[r] + d1b[r];
    s2 += d1a[r] * d1a[r] + d1b[r] * d1b[r];
  }
  s += __shfl_xor(s, 32);  s2 += __shfl_xor(s2, 32);
  float mean = s * 0.015625f;
  float rs = rsqrtf(s2 * 0.015625f - mean * mean + 1e-5f);
  // ---- z split -> LDS rows [32 tok][272B]: hi bytes [0,128), lo [128,256)
#pragma unroll
  for (int rq = 0; rq < 4; ++rq) {
    unsigned h0, l0, h1, l1;
    split2((d1a[rq * 4 + 0] - mean) * rs, (d1a[rq * 4 + 1] - mean) * rs, h0, l0);
    split2((d1a[rq * 4 + 2] - mean) * rs, (d1a[rq * 4 + 3] - mean) * rs, h1, l1);
    *(uint2*)(h2b + l31 * 272 + rq * 16 + hi * 8) = make_uint2(h0, h1);
    *(uint2*)(h2b + l31 * 272 + 128 + rq * 16 + hi * 8) = make_uint2(l0, l1);
    split2((d1b[rq * 4 + 0] - mean) * rs, (d1b[rq * 4 + 1] - mean) * rs, h0, l0);
    split2((d1b[rq * 4 + 2] - mean) * rs, (d1b[rq * 4 + 3] - mean) * rs, h1, l1);
    *(uint2*)(h2b + l31 * 272 + 64 + rq * 16 + hi * 8) = make_uint2(h0, h1);
    *(uint2*)(h2b + l31 * 272 + 192 + rq * 16 + hi * 8) = make_uint2(l0, l1);
  }
  bf16x8 hfh[4], hfl[4];
#pragma unroll
  for (int ks = 0; ks < 4; ++ks) {
    hfh[ks] = __builtin_bit_cast(bf16x8, *(const uint4*)(h2b + l31 * 272 + ks * 32 + hi * 16));
    hfl[ks] = __builtin_bit_cast(bf16x8, *(const uint4*)(h2b + l31 * 272 + 128 + ks * 32 + hi * 16));
  }
  // ---- GEMM2+3 chained per 32-outch U tile (both split)
  f32x16 d3a = Z16, d3b = Z16;
#pragma unroll 1
  for (int tt = 0; tt < 8; ++tt) {
    f32x16 u = Z16;
#pragma unroll
    for (int ks = 0; ks < 4; ++ks) {
      bf16x8 wh = LDA(w1P, tt * 4 + ks), wl = LDA(w1P, 32 + tt * 4 + ks);
      u = MF(wh, hfh[ks], u); u = MF(wh, hfl[ks], u); u = MF(wl, hfh[ks], u);
    }
#pragma unroll
    for (int r = 0; r < 16; ++r) {
      int ch = tt * 32 + (r & 3) + 8 * (r >> 2) + 4 * hi;
      u[r] = fmaxf(u[r] + bias[128 + ch], 0.f);
    }
#pragma unroll
    for (int rq = 0; rq < 4; ++rq) {
      unsigned h0, l0, h1, l1;
      split2(u[rq * 4 + 0], u[rq * 4 + 1], h0, l0);
      split2(u[rq * 4 + 2], u[rq * 4 + 3], h1, l1);
      *(uint2*)(pub + l31 * 144 + rq * 16 + hi * 8) = make_uint2(h0, h1);
      *(uint2*)(pub + l31 * 144 + 64 + rq * 16 + hi * 8) = make_uint2(l0, l1);
    }
    bf16x8 uh0 = __builtin_bit_cast(bf16x8, *(const uint4*)(pub + l31 * 144 + hi * 16));
    bf16x8 uh1 = __builtin_bit_cast(bf16x8, *(const uint4*)(pub + l31 * 144 + 32 + hi * 16));
    bf16x8 ul0 = __builtin_bit_cast(bf16x8, *(const uint4*)(pub + l31 * 144 + 64 + hi * 16));
    bf16x8 ul1 = __builtin_bit_cast(bf16x8, *(const uint4*)(pub + l31 * 144 + 96 + hi * 16));
    bf16x8 w2h0 = LDA(w2P, tt * 2),      w2h1 = LDA(w2P, tt * 2 + 1);
    bf16x8 w2l0 = LDA(w2P, 32 + tt * 2), w2l1 = LDA(w2P, 32 + tt * 2 + 1);
    d3a = MF(w2h0, uh0, d3a); d3a = MF(w2h0, ul0, d3a); d3a = MF(w2l0, uh0, d3a);
    d3a = MF(w2h1, uh1, d3a); d3a = MF(w2h1, ul1, d3a); d3a = MF(w2l1, uh1, d3a);
    bf16x8 w2h2 = LDA(w2P, 16 + tt * 2),      w2h3 = LDA(w2P, 16 + tt * 2 + 1);
    bf16x8 w2l2 = LDA(w2P, 48 + tt * 2),      w2l3 = LDA(w2P, 48 + tt * 2 + 1);
    d3b = MF(w2h2, uh0, d3b); d3b = MF(w2h2, ul0, d3b); d3b = MF(w2l2, uh0, d3b);
    d3b = MF(w2h3, uh1, d3b); d3b = MF(w2h3, ul1, d3b); d3b = MF(w2l3, uh1, d3b);
  }
  // ---- epilogue: out = d3 + b2 + R; transpose via LDS [32 tok][272B]; coalesced store
#pragma unroll
  for (int rq = 0; rq < 4; ++rq) {
    int ca = rq * 8 + hi * 4, cb = 32 + rq * 8 + hi * 4;
    float4 va, vb;
    va.x = d3a[rq * 4 + 0] + bias[64 + ca + 0] + d1a[rq * 4 + 0];
    va.y = d3a[rq * 4 + 1] + bias[64 + ca + 1] + d1a[rq * 4 + 1];
    va.z = d3a[rq * 4 + 2] + bias[64 + ca + 2] + d1a[rq * 4 + 2];
    va.w = d3a[rq * 4 + 3] + bias[64 + ca + 3] + d1a[rq * 4 + 3];
    vb.x = d3b[rq * 4 + 0] + bias[64 + cb + 0] + d1b[rq * 4 + 0];
    vb.y = d3b[rq * 4 + 1] + bias[64 + cb + 1] + d1b[rq * 4 + 1];
    vb.z = d3b[rq * 4 + 2] + bias[64 + cb + 2] + d1b[rq * 4 + 2];
    vb.w = d3b[rq * 4 + 3] + bias[64 + cb + 3] + d1b[rq * 4 + 3];
    *(float4*)(h2b + l31 * 272 + rq * 32 + hi * 16) = va;
    *(float4*)(h2b + l31 * 272 + 128 + rq * 32 + hi * 16) = vb;
  }
  float* gout = out + ((size_t)(b * Nn + n) * Tn + tt_time) * 64 + hi * 32;
#pragma unroll
  for (int i = 0; i < 8; ++i)
    *(float4*)(gout + i * 4) = *(float4*)(h2b + l31 * 272 + hi * 128 + i * 16);
#undef LDA
#undef MF
}

// ---------------------------------------------------------------- launch
extern "C" void kernel_launch(void* const* d_in, const int* in_sizes, int n_in,
                              void* d_out, int out_size, void* d_ws, size_t ws_size,
                              hipStream_t stream) {
  const float* x   = (const float*)d_in[0];
  const int* adj   = (const int*)d_in[1];
  const float* wq  = (const float*)d_in[2];
  const float* wk  = (const float*)d_in[3];
  const float* wv  = (const float*)d_in[4];
  const float* wo  = (const float*)d_in[5];
  const float* bo  = (const float*)d_in[6];
  const float* w1  = (const float*)d_in[7];
  const float* b1  = (const float*)d_in[8];
  const float* w2  = (const float*)d_in[9];
  const float* b2  = (const float*)d_in[10];
  const float* g1  = (const float*)d_in[11];
  const float* be1 = (const float*)d_in[12];
  const float* g2  = (const float*)d_in[13];
  const float* be2 = (const float*)d_in[14];
  float* out = (float*)d_out;

  float* ws = (float*)d_ws;
  unsigned long long* packed = (unsigned long long*)ws;        // 128 KB
  __hip_bfloat16* Qb = (__hip_bfloat16*)(ws + 32768);          // [96][1024][16] bf16
  __hip_bfloat16* Kb = (__hip_bfloat16*)(ws + 819200);
  __hip_bfloat16* Vt = (__hip_bfloat16*)(ws + 1605632);        // [96][16][1024]
  float* O = ws + 2392064;                                     // [24576][64] f32
  __hip_bfloat16* woP = (__hip_bfloat16*)(ws + 3964928);       // 8192 bf16 (hi+lo)
  __hip_bfloat16* w1P = (__hip_bfloat16*)(ws + 3969024);       // 32768 bf16 (hi+lo)
  __hip_bfloat16* w2P = (__hip_bfloat16*)(ws + 3985408);       // 32768 bf16 (hi+lo)
  float* b1p = ws + 4001792;                                   // 256 f32; end ~16 MB

  k_pack<<<4096, 256, 0, stream>>>(adj, packed);
  k_prep<<<19, 256, 0, stream>>>(wo, w1, w2, b1, g2, be2, woP, w1P, w2P, b1p);
  k_ln1_qkv<<<384, 256, 0, stream>>>(x, wq, wk, wv, g1, be1, Qb, Kb, Vt);
  k_attn<<<768, 256, 0, stream>>>(Qb, Kb, Vt, (const unsigned*)packed, O);
  k_tail<<<768, 64, 0, stream>>>(O, x, woP, w1P, w2P, bo, b1p, b2, out);
}

// Round 10
// 175.245 us; speedup vs baseline: 2.0330x; 1.0290x over previous
//
#include <hip/hip_runtime.h>
#include <hip/hip_bf16.h>

#define DEV __device__ __forceinline__

constexpr int Nn = 1024, Tn = 12, Dn = 64;

#if __has_builtin(__builtin_amdgcn_exp2f)
DEV float fast_exp2(float x) { return __builtin_amdgcn_exp2f(x); }
#else
DEV float fast_exp2(float x) { return exp2f(x); }
#endif

typedef __bf16 bf16x8 __attribute__((ext_vector_type(8)));
typedef __bf16 bf16x2 __attribute__((ext_vector_type(2)));
typedef float f32x4 __attribute__((ext_vector_type(4)));
typedef float f32x16 __attribute__((ext_vector_type(16)));

#define Z16 {0.f,0.f,0.f,0.f, 0.f,0.f,0.f,0.f, 0.f,0.f,0.f,0.f, 0.f,0.f,0.f,0.f}

DEV unsigned f2b(float f) {  // f32 -> bf16 bits (round-half-up)
  unsigned u = __builtin_bit_cast(unsigned, f);
  return (u + 0x8000u) >> 16;
}
DEV unsigned pk2(float a, float b) { return f2b(a) | (f2b(b) << 16); }
DEV float b2f(unsigned hbits) { return __builtin_bit_cast(float, hbits << 16); }
// split pair into hi word + lo word (two-term bf16 representation)
DEV void split2(float a, float b, unsigned& hw, unsigned& lw) {
  unsigned ha = f2b(a), hb = f2b(b);
  hw = ha | (hb << 16);
  lw = pk2(a - b2f(ha), b - b2f(hb));
}

DEV void wave_reduce2(float& s, float& s2) {
#pragma unroll
  for (int off = 32; off; off >>= 1) {
    s += __shfl_xor(s, off, 64);
    s2 += __shfl_xor(s2, off, 64);
  }
}

// ---------------------------------------------------------------- pack adj
__global__ __launch_bounds__(256) void k_pack(const int* __restrict__ adj,
                                              unsigned long long* __restrict__ packed) {
  int gw = (blockIdx.x * 256 + threadIdx.x) >> 6;
  int lane = threadIdx.x & 63;
  int v = adj[(gw << 6) + lane];
  unsigned long long m = __ballot(v != 0);
  if (lane == 0) packed[gw] = m;
}

// ---------------------------------------------------------------- bias table (mask -> C-frag order)
// biasF[tile(qb32*32+kt)][c(4)][lane(64)][4] f32: 0 if adj(q,key)!=0 else -1e30.
// q = qb32*32 + (lane&31); key = kt*32 + (r&3)+8*(r>>2)+4*(lane>>5), r = c*4+i.
__global__ __launch_bounds__(256) void k_bias(const unsigned* __restrict__ packed32,
                                              float* __restrict__ biasF) {
  int tid = blockIdx.x * 256 + threadIdx.x;   // 65536 threads
  int tile = tid >> 6, lane = tid & 63;
  int qb32 = tile >> 5, kt = tile & 31;
  int l31 = lane & 31, hi = lane >> 5;
  unsigned mm = packed32[(size_t)(qb32 * 32 + l31) * 32 + kt] >> (hi * 4);
  float* base = biasF + (size_t)tile * 1024 + lane * 4;
#pragma unroll
  for (int c = 0; c < 4; ++c) {
    float4 v;
    v.x = ((mm >> (((c * 4 + 0) & 3) + 8 * ((c * 4 + 0) >> 2))) & 1u) ? 0.f : -1e30f;
    v.y = ((mm >> (((c * 4 + 1) & 3) + 8 * ((c * 4 + 1) >> 2))) & 1u) ? 0.f : -1e30f;
    v.z = ((mm >> (((c * 4 + 2) & 3) + 8 * ((c * 4 + 2) >> 2))) & 1u) ? 0.f : -1e30f;
    v.w = ((mm >> (((c * 4 + 3) & 3) + 8 * ((c * 4 + 3) >> 2))) & 1u) ? 0.f : -1e30f;
    *(float4*)(base + c * 256) = v;
  }
}

// ---------------------------------------------------------------- prep: frag-pack weights, hi+lo [unchanged]
__global__ __launch_bounds__(256) void k_prep(
    const float* __restrict__ wo, const float* __restrict__ w1,
    const float* __restrict__ w2, const float* __restrict__ b1,
    const float* __restrict__ g2, const float* __restrict__ be2,
    __hip_bfloat16* __restrict__ woP, __hip_bfloat16* __restrict__ w1P,
    __hip_bfloat16* __restrict__ w2P, float* __restrict__ b1p) {
  int tid = blockIdx.x * 256 + threadIdx.x;
  if (tid < 512) {
    int fg = tid >> 6, lane = tid & 63;
    int t = fg >> 2, ks = fg & 3, hi = lane >> 5, l31 = lane & 31;
    unsigned hw[4], lw[4];
#pragma unroll
    for (int jj = 0; jj < 4; ++jj) {
      int k = ks * 16 + hi * 8 + jj * 2;
      split2(wo[k * 64 + t * 32 + l31], wo[(k + 1) * 64 + t * 32 + l31], hw[jj], lw[jj]);
    }
    *(uint4*)(woP + (size_t)tid * 8) = make_uint4(hw[0], hw[1], hw[2], hw[3]);
    *(uint4*)(woP + (size_t)(512 + tid) * 8) = make_uint4(lw[0], lw[1], lw[2], lw[3]);
  } else if (tid < 2560) {
    int id = tid - 512;
    int fg = id >> 6, lane = id & 63;
    int tile = fg >> 2, ks = fg & 3, hi = lane >> 5, l31 = lane & 31;
    unsigned hw[4], lw[4];
#pragma unroll
    for (int jj = 0; jj < 4; ++jj) {
      int k = ks * 16 + hi * 8 + jj * 2;
      split2(g2[k] * w1[k * 256 + tile * 32 + l31],
             g2[k + 1] * w1[(k + 1) * 256 + tile * 32 + l31], hw[jj], lw[jj]);
    }
    *(uint4*)(w1P + (size_t)id * 8) = make_uint4(hw[0], hw[1], hw[2], hw[3]);
    *(uint4*)(w1P + (size_t)(2048 + id) * 8) = make_uint4(lw[0], lw[1], lw[2], lw[3]);
  } else if (tid < 4608) {
    int id = tid - 2560;
    int fg = id >> 6, lane = id & 63;
    int t = fg >> 4, ks = fg & 15, hi = lane >> 5, l31 = lane & 31;
    unsigned hw[4], lw[4];
#pragma unroll
    for (int jj = 0; jj < 4; ++jj) {
      int k = ks * 16 + hi * 8 + jj * 2;
      split2(w2[k * 64 + t * 32 + l31], w2[(k + 1) * 64 + t * 32 + l31], hw[jj], lw[jj]);
    }
    *(uint4*)(w2P + (size_t)id * 8) = make_uint4(hw[0], hw[1], hw[2], hw[3]);
    *(uint4*)(w2P + (size_t)(2048 + id) * 8) = make_uint4(lw[0], lw[1], lw[2], lw[3]);
  } else if (tid < 4864) {
    int o = tid - 4608;
    float s = b1[o];
    for (int c = 0; c < 64; ++c) s += be2[c] * w1[c * 256 + o];
    b1p[o] = s;
  }
}

// ---------------------------------------------------------------- LN1 + QKV (bf16 out) [unchanged]
__global__ __launch_bounds__(256) void k_ln1_qkv(
    const float* __restrict__ x, const float* __restrict__ wq,
    const float* __restrict__ wk, const float* __restrict__ wv,
    const float* __restrict__ g1, const float* __restrict__ be1,
    __hip_bfloat16* __restrict__ Qb, __hip_bfloat16* __restrict__ Kb,
    __hip_bfloat16* __restrict__ Vt) {
  __shared__ float wlds[64 * 192];
  __shared__ float hlds[4][16][68];   // wave-private
  int tid = threadIdx.x, lane = tid & 63, w = tid >> 6;
  for (int i = tid * 4; i < 4096; i += 1024) {
    int c = i >> 6, d = i & 63;
    *(float4*)&wlds[c * 192 + d]       = *(const float4*)&wq[i];
    *(float4*)&wlds[c * 192 + 64 + d]  = *(const float4*)&wk[i];
    *(float4*)&wlds[c * 192 + 128 + d] = *(const float4*)&wv[i];
  }
  float g = g1[lane], be = be1[lane];
  __syncthreads();
  int row0 = blockIdx.x * 64 + w * 16;
  int bt = row0 >> 10, n0 = row0 & 1023;
#pragma unroll 1
  for (int r = 0; r < 16; ++r) {
    int n = n0 + r;
    int b = bt / Tn, t = bt - b * Tn;
    float xv = x[((b * Nn + n) * Tn + t) * 64 + lane];
    float s = xv, s2 = xv * xv;
    wave_reduce2(s, s2);
    float mean = s * 0.015625f;
    float var = s2 * 0.015625f - mean * mean;
    float rs = rsqrtf(var + 1e-5f);
    hlds[w][r][lane] = (xv - mean) * rs * g + be;
  }
  float qa[16], ka[16], va[16];
#pragma unroll
  for (int r = 0; r < 16; ++r) { qa[r] = 0.f; ka[r] = 0.f; va[r] = 0.f; }
  for (int c = 0; c < 64; c += 4) {
    float wq4[4], wk4[4], wv4[4];
#pragma unroll
    for (int cc = 0; cc < 4; ++cc) {
      wq4[cc] = wlds[(c + cc) * 192 + lane];
      wk4[cc] = wlds[(c + cc) * 192 + 64 + lane];
      wv4[cc] = wlds[(c + cc) * 192 + 128 + lane];
    }
#pragma unroll
    for (int r = 0; r < 16; ++r) {
      float4 h4 = *(float4*)&hlds[w][r][c];
      qa[r] = fmaf(h4.x, wq4[0], qa[r]); qa[r] = fmaf(h4.y, wq4[1], qa[r]);
      qa[r] = fmaf(h4.z, wq4[2], qa[r]); qa[r] = fmaf(h4.w, wq4[3], qa[r]);
      ka[r] = fmaf(h4.x, wk4[0], ka[r]); ka[r] = fmaf(h4.y, wk4[1], ka[r]);
      ka[r] = fmaf(h4.z, wk4[2], ka[r]); ka[r] = fmaf(h4.w, wk4[3], ka[r]);
      va[r] = fmaf(h4.x, wv4[0], va[r]); va[r] = fmaf(h4.y, wv4[1], va[r]);
      va[r] = fmaf(h4.z, wv4[2], va[r]); va[r] = fmaf(h4.w, wv4[3], va[r]);
    }
  }
  const float QS = 0.25f * 1.44269504088896f;  // 1/sqrt(HD) * log2(e)
  int hh = lane >> 4, cc = lane & 15;
#pragma unroll 1
  for (int r = 0; r < 16; ++r) {
    int n = n0 + r;
    size_t idx = ((size_t)(bt * 4 + hh) * 1024 + n) * 16 + cc;
    Qb[idx] = __hip_bfloat16_raw{(unsigned short)f2b(qa[r] * QS)};
    Kb[idx] = __hip_bfloat16_raw{(unsigned short)f2b(ka[r])};
  }
#pragma unroll
  for (int r = 0; r < 16; ++r) hlds[w][r][lane] = va[r];
  unsigned os[8];
#pragma unroll
  for (int j = 0; j < 8; ++j)
    os[j] = f2b(hlds[w][2 * j][lane]) | (f2b(hlds[w][2 * j + 1][lane]) << 16);
  uint4* vo = (uint4*)(Vt + ((size_t)(bt * 4 + hh) * 16 + cc) * 1024 + n0);
  vo[0] = make_uint4(os[0], os[1], os[2], os[3]);
  vo[1] = make_uint4(os[4], os[5], os[6], os[7]);
}

// ---------------------------------------------------------------- attention (MFMA, bias-C + defer-max)
// Per 32-key tile: S^T = mfma(K, Q^T, C=mask-bias frag)  -> zero mask VALU.
// Defer-max (THR=8): rescale only when the tile max exceeds m+8 (wave-uniform).
// P packed via (__bf16) casts (compiler v_cvt_pk_bf16_f32); P rows 72B (2-way banks).
__global__ __launch_bounds__(256) void k_attn(
    const __hip_bfloat16* __restrict__ Qb, const __hip_bfloat16* __restrict__ Kb,
    const __hip_bfloat16* __restrict__ Vt, const float* __restrict__ biasF,
    float* __restrict__ O) {
  __shared__ uint4 smem[4][160];  // per wave: P rows 32x72B; epilogue overlays 32x80B
  int bid = (blockIdx.x & 7) * 96 + (blockIdx.x >> 3);  // XCD-chunked (768%8==0)
  int bth = bid >> 3, qb = bid & 7;
  int bt = bth >> 2, h = bth & 3;
  int tid = threadIdx.x, lane = tid & 63, w = tid >> 6;
  int l15 = lane & 15, l31 = lane & 31, hi = lane >> 5, g4 = lane >> 4;
  int q0 = qb * 128 + w * 32;
  bf16x8 qfrag = __builtin_bit_cast(bf16x8,
      *(const uint4*)(Qb + ((size_t)bth * 1024 + q0 + l31) * 16 + hi * 8));
  const uint4* kbase = (const uint4*)(Kb + (size_t)bth * 1024 * 16);
  const uint4* vtb = (const uint4*)(Vt + (size_t)bth * 16 * 1024);
  const float* bbase = biasF + ((size_t)(qb * 4 + w) * 32) * 1024 + lane * 4;
  char* myp = (char*)&smem[w][0];

  f32x4 o1 = {0.f, 0.f, 0.f, 0.f}, o2 = {0.f, 0.f, 0.f, 0.f};
  float m = -3e38f, lsum = 0.f;
  uint4 kf = kbase[l31 * 2 + hi];
  uint4 vf = vtb[l15 * 128 + g4];
  f32x4 bf0 = *(const f32x4*)(bbase + 0);
  f32x4 bf1 = *(const f32x4*)(bbase + 256);
  f32x4 bf2 = *(const f32x4*)(bbase + 512);
  f32x4 bf3 = *(const f32x4*)(bbase + 768);
#pragma unroll 1
  for (int kt = 0; kt < 32; ++kt) {
    int ktn = kt < 31 ? kt + 1 : 31;  // clamped prefetch
    uint4 kf_n = kbase[ktn * 64 + l31 * 2 + hi];
    uint4 vf_n = vtb[l15 * 128 + ktn * 4 + g4];
    const float* bbn = bbase + (size_t)ktn * 1024;
    f32x4 bn0 = *(const f32x4*)(bbn + 0);
    f32x4 bn1 = *(const f32x4*)(bbn + 256);
    f32x4 bn2 = *(const f32x4*)(bbn + 512);
    f32x4 bn3 = *(const f32x4*)(bbn + 768);
    // C-init = mask bias (0 / -1e30) in exact fragment order
    f32x16 s = {bf0.x, bf0.y, bf0.z, bf0.w, bf1.x, bf1.y, bf1.z, bf1.w,
                bf2.x, bf2.y, bf2.z, bf2.w, bf3.x, bf3.y, bf3.z, bf3.w};
    s = __builtin_amdgcn_mfma_f32_32x32x16_bf16(
        __builtin_bit_cast(bf16x8, kf), qfrag, s, 0, 0, 0);
    // tile max (max3-friendly tree) + cross-half combine
    float t0 = fmaxf(fmaxf(s[0], s[1]), s[2]);
    float t1 = fmaxf(fmaxf(s[3], s[4]), s[5]);
    float t2 = fmaxf(fmaxf(s[6], s[7]), s[8]);
    float t3 = fmaxf(fmaxf(s[9], s[10]), s[11]);
    float t4 = fmaxf(fmaxf(s[12], s[13]), s[14]);
    float tm = fmaxf(fmaxf(fmaxf(t0, t1), t2), fmaxf(fmaxf(t3, t4), s[15]));
    tm = fmaxf(tm, __shfl_xor(tm, 32));
    float mn = fmaxf(m, tm);
    if (!__all(mn <= m + 8.f)) {       // defer-max: rescale only on real growth
      float sc = fast_exp2(m - mn);
      m = mn;
      lsum *= sc;
      float sc1 = __shfl(sc, l15), sc2 = __shfl(sc, l15 + 16);
#pragma unroll
      for (int r = 0; r < 4; ++r) { o1[r] *= sc1; o2[r] *= sc2; }
    }
    float p[16];
#pragma unroll
    for (int r = 0; r < 16; ++r) { p[r] = fast_exp2(s[r] - m); lsum += p[r]; }
    unsigned pw[8];
#pragma unroll
    for (int j = 0; j < 8; ++j) {
      bf16x2 t = {(__bf16)p[2 * j], (__bf16)p[2 * j + 1]};  // -> v_cvt_pk_bf16_f32
      pw[j] = __builtin_bit_cast(unsigned, t);
    }
    char* wp = myp + l31 * 72 + hi * 8;   // 72B rows: 2-way banks (free)
    *(uint2*)(wp +  0) = make_uint2(pw[0], pw[1]);
    *(uint2*)(wp + 16) = make_uint2(pw[2], pw[3]);
    *(uint2*)(wp + 32) = make_uint2(pw[4], pw[5]);
    *(uint2*)(wp + 48) = make_uint2(pw[6], pw[7]);
    uint4 b1v = *(uint4*)(myp + l15 * 72 + g4 * 16);
    uint4 b2v = *(uint4*)(myp + (l15 + 16) * 72 + g4 * 16);
    bf16x8 vfrag = __builtin_bit_cast(bf16x8, vf);
    o1 = __builtin_amdgcn_mfma_f32_16x16x32_bf16(
        vfrag, __builtin_bit_cast(bf16x8, b1v), o1, 0, 0, 0);
    o2 = __builtin_amdgcn_mfma_f32_16x16x32_bf16(
        vfrag, __builtin_bit_cast(bf16x8, b2v), o2, 0, 0, 0);
    kf = kf_n; vf = vf_n;
    bf0 = bn0; bf1 = bn1; bf2 = bn2; bf3 = bn3;
  }
  float lt = lsum + __shfl_xor(lsum, 32);
  float inv = lt > 0.f ? 1.f / lt : 0.f;
  float inv1 = __shfl(inv, l15), inv2 = __shfl(inv, l15 + 16);
  float* of = (float*)myp;
#pragma unroll
  for (int r = 0; r < 4; ++r) {
    of[l15 * 20 + g4 * 4 + r] = o1[r] * inv1;
    of[(l15 + 16) * 20 + g4 * 4 + r] = o2[r] * inv2;
  }
  float* orow = O + ((size_t)bt * 1024 + q0 + l31) * 64 + h * 16 + hi * 8;
  *(float4*)(orow)     = *(float4*)(myp + l31 * 80 + hi * 32);
  *(float4*)(orow + 4) = *(float4*)(myp + l31 * 80 + hi * 32 + 16);
}

// ---------------------------------------------------------------- fused tail (split-bf16 MFMA) [unchanged]
__global__ __launch_bounds__(64) void k_tail(
    const float* __restrict__ O, const float* __restrict__ x,
    const __hip_bfloat16* __restrict__ woP, const __hip_bfloat16* __restrict__ w1P,
    const __hip_bfloat16* __restrict__ w2P, const float* __restrict__ bo,
    const float* __restrict__ b1p, const float* __restrict__ b2,
    float* __restrict__ out) {
  __shared__ float bias[384];     // [0,64) bo, [64,128) b2, [128,384) b1p
  __shared__ char wbuf[13312];
  int lane = threadIdx.x & 63;
  int l31 = lane & 31, hi = lane >> 5;
  for (int i = threadIdx.x; i < 384; i += 64)
    bias[i] = i < 64 ? bo[i] : (i < 128 ? b2[i - 64] : b1p[i - 128]);
  __syncthreads();

  int tok = blockIdx.x * 32 + l31;
  int bt = tok >> 10, n = tok & 1023;
  int b = bt / Tn, tt_time = bt - b * Tn;
  const float* orow = O + (size_t)tok * 64;
  const float* xrow = x + ((size_t)(b * Nn + n) * Tn + tt_time) * 64;
  char* h2b = wbuf;
  char* pub = wbuf + 8704;

#define LDA(base, g) __builtin_bit_cast(bf16x8, *(const uint4*)((base) + ((size_t)(g) * 64 + lane) * 8))
#define MF(A, B, C) __builtin_amdgcn_mfma_f32_32x32x16_bf16(A, B, C, 0, 0, 0)

  bf16x8 ofh[4], ofl[4];
#pragma unroll
  for (int ks = 0; ks < 4; ++ks) {
    float4 oa = *(const float4*)(orow + ks * 16 + hi * 8);
    float4 ob = *(const float4*)(orow + ks * 16 + hi * 8 + 4);
    unsigned hw[4], lw[4];
    split2(oa.x, oa.y, hw[0], lw[0]); split2(oa.z, oa.w, hw[1], lw[1]);
    split2(ob.x, ob.y, hw[2], lw[2]); split2(ob.z, ob.w, hw[3], lw[3]);
    ofh[ks] = __builtin_bit_cast(bf16x8, make_uint4(hw[0], hw[1], hw[2], hw[3]));
    ofl[ks] = __builtin_bit_cast(bf16x8, make_uint4(lw[0], lw[1], lw[2], lw[3]));
  }
  f32x16 d1a = Z16, d1b = Z16;
#pragma unroll
  for (int ks = 0; ks < 4; ++ks) {
    bf16x8 wha = LDA(woP, ks), wla = LDA(woP, 8 + ks);
    d1a = MF(wha, ofh[ks], d1a); d1a = MF(wha, ofl[ks], d1a); d1a = MF(wla, ofh[ks], d1a);
    bf16x8 whb = LDA(woP, 4 + ks), wlb = LDA(woP, 12 + ks);
    d1b = MF(whb, ofh[ks], d1b); d1b = MF(whb, ofl[ks], d1b); d1b = MF(wlb, ofh[ks], d1b);
  }
#pragma unroll
  for (int rq = 0; rq < 4; ++rq) {
    float4 xa = *(const float4*)(xrow + rq * 8 + hi * 4);
    float4 xb = *(const float4*)(xrow + 32 + rq * 8 + hi * 4);
    int ca = rq * 8 + hi * 4, cb = 32 + rq * 8 + hi * 4;
    d1a[rq * 4 + 0] += bias[ca + 0] + xa.x;  d1a[rq * 4 + 1] += bias[ca + 1] + xa.y;
    d1a[rq * 4 + 2] += bias[ca + 2] + xa.z;  d1a[rq * 4 + 3] += bias[ca + 3] + xa.w;
    d1b[rq * 4 + 0] += bias[cb + 0] + xb.x;  d1b[rq * 4 + 1] += bias[cb + 1] + xb.y;
    d1b[rq * 4 + 2] += bias[cb + 2] + xb.z;  d1b[rq * 4 + 3] += bias[cb + 3] + xb.w;
  }
  float s = 0.f, s2 = 0.f;
#pragma unroll
  for (int r = 0; r < 16; ++r) {
    s += d1a[r] + d1b[r];
    s2 += d1a[r] * d1a[r] + d1b[r] * d1b[r];
  }
  s += __shfl_xor(s, 32);  s2 += __shfl_xor(s2, 32);
  float mean = s * 0.015625f;
  float rs = rsqrtf(s2 * 0.015625f - mean * mean + 1e-5f);
#pragma unroll
  for (int rq = 0; rq < 4; ++rq) {
    unsigned h0, l0, h1, l1;
    split2((d1a[rq * 4 + 0] - mean) * rs, (d1a[rq * 4 + 1] - mean) * rs, h0, l0);
    split2((d1a[rq * 4 + 2] - mean) * rs, (d1a[rq * 4 + 3] - mean) * rs, h1, l1);
    *(uint2*)(h2b + l31 * 272 + rq * 16 + hi * 8) = make_uint2(h0, h1);
    *(uint2*)(h2b + l31 * 272 + 128 + rq * 16 + hi * 8) = make_uint2(l0, l1);
    split2((d1b[rq * 4 + 0] - mean) * rs, (d1b[rq * 4 + 1] - mean) * rs, h0, l0);
    split2((d1b[rq * 4 + 2] - mean) * rs, (d1b[rq * 4 + 3] - mean) * rs, h1, l1);
    *(uint2*)(h2b + l31 * 272 + 64 + rq * 16 + hi * 8) = make_uint2(h0, h1);
    *(uint2*)(h2b + l31 * 272 + 192 + rq * 16 + hi * 8) = make_uint2(l0, l1);
  }
  bf16x8 hfh[4], hfl[4];
#pragma unroll
  for (int ks = 0; ks < 4; ++ks) {
    hfh[ks] = __builtin_bit_cast(bf16x8, *(const uint4*)(h2b + l31 * 272 + ks * 32 + hi * 16));
    hfl[ks] = __builtin_bit_cast(bf16x8, *(const uint4*)(h2b + l31 * 272 + 128 + ks * 32 + hi * 16));
  }
  f32x16 d3a = Z16, d3b = Z16;
#pragma unroll 1
  for (int tt = 0; tt < 8; ++tt) {
    f32x16 u = Z16;
#pragma unroll
    for (int ks = 0; ks < 4; ++ks) {
      bf16x8 wh = LDA(w1P, tt * 4 + ks), wl = LDA(w1P, 32 + tt * 4 + ks);
      u = MF(wh, hfh[ks], u); u = MF(wh, hfl[ks], u); u = MF(wl, hfh[ks], u);
    }
#pragma unroll
    for (int r = 0; r < 16; ++r) {
      int ch = tt * 32 + (r & 3) + 8 * (r >> 2) + 4 * hi;
      u[r] = fmaxf(u[r] + bias[128 + ch], 0.f);
    }
#pragma unroll
    for (int rq = 0; rq < 4; ++rq) {
      unsigned h0, l0, h1, l1;
      split2(u[rq * 4 + 0], u[rq * 4 + 1], h0, l0);
      split2(u[rq * 4 + 2], u[rq * 4 + 3], h1, l1);
      *(uint2*)(pub + l31 * 144 + rq * 16 + hi * 8) = make_uint2(h0, h1);
      *(uint2*)(pub + l31 * 144 + 64 + rq * 16 + hi * 8) = make_uint2(l0, l1);
    }
    bf16x8 uh0 = __builtin_bit_cast(bf16x8, *(const uint4*)(pub + l31 * 144 + hi * 16));
    bf16x8 uh1 = __builtin_bit_cast(bf16x8, *(const uint4*)(pub + l31 * 144 + 32 + hi * 16));
    bf16x8 ul0 = __builtin_bit_cast(bf16x8, *(const uint4*)(pub + l31 * 144 + 64 + hi * 16));
    bf16x8 ul1 = __builtin_bit_cast(bf16x8, *(const uint4*)(pub + l31 * 144 + 96 + hi * 16));
    bf16x8 w2h0 = LDA(w2P, tt * 2),      w2h1 = LDA(w2P, tt * 2 + 1);
    bf16x8 w2l0 = LDA(w2P, 32 + tt * 2), w2l1 = LDA(w2P, 32 + tt * 2 + 1);
    d3a = MF(w2h0, uh0, d3a); d3a = MF(w2h0, ul0, d3a); d3a = MF(w2l0, uh0, d3a);
    d3a = MF(w2h1, uh1, d3a); d3a = MF(w2h1, ul1, d3a); d3a = MF(w2l1, uh1, d3a);
    bf16x8 w2h2 = LDA(w2P, 16 + tt * 2),      w2h3 = LDA(w2P, 16 + tt * 2 + 1);
    bf16x8 w2l2 = LDA(w2P, 48 + tt * 2),      w2l3 = LDA(w2P, 48 + tt * 2 + 1);
    d3b = MF(w2h2, uh0, d3b); d3b = MF(w2h2, ul0, d3b); d3b = MF(w2l2, uh0, d3b);
    d3b = MF(w2h3, uh1, d3b); d3b = MF(w2h3, ul1, d3b); d3b = MF(w2l3, uh1, d3b);
  }
#pragma unroll
  for (int rq = 0; rq < 4; ++rq) {
    int ca = rq * 8 + hi * 4, cb = 32 + rq * 8 + hi * 4;
    float4 va, vb;
    va.x = d3a[rq * 4 + 0] + bias[64 + ca + 0] + d1a[rq * 4 + 0];
    va.y = d3a[rq * 4 + 1] + bias[64 + ca + 1] + d1a[rq * 4 + 1];
    va.z = d3a[rq * 4 + 2] + bias[64 + ca + 2] + d1a[rq * 4 + 2];
    va.w = d3a[rq * 4 + 3] + bias[64 + ca + 3] + d1a[rq * 4 + 3];
    vb.x = d3b[rq * 4 + 0] + bias[64 + cb + 0] + d1b[rq * 4 + 0];
    vb.y = d3b[rq * 4 + 1] + bias[64 + cb + 1] + d1b[rq * 4 + 1];
    vb.z = d3b[rq * 4 + 2] + bias[64 + cb + 2] + d1b[rq * 4 + 2];
    vb.w = d3b[rq * 4 + 3] + bias[64 + cb + 3] + d1b[rq * 4 + 3];
    *(float4*)(h2b + l31 * 272 + rq * 32 + hi * 16) = va;
    *(float4*)(h2b + l31 * 272 + 128 + rq * 32 + hi * 16) = vb;
  }
  float* gout = out + ((size_t)(b * Nn + n) * Tn + tt_time) * 64 + hi * 32;
#pragma unroll
  for (int i = 0; i < 8; ++i)
    *(float4*)(gout + i * 4) = *(float4*)(h2b + l31 * 272 + hi * 128 + i * 16);
#undef LDA
#undef MF
}

// ---------------------------------------------------------------- launch
extern "C" void kernel_launch(void* const* d_in, const int* in_sizes, int n_in,
                              void* d_out, int out_size, void* d_ws, size_t ws_size,
                              hipStream_t stream) {
  const float* x   = (const float*)d_in[0];
  const int* adj   = (const int*)d_in[1];
  const float* wq  = (const float*)d_in[2];
  const float* wk  = (const float*)d_in[3];
  const float* wv  = (const float*)d_in[4];
  const float* wo  = (const float*)d_in[5];
  const float* bo  = (const float*)d_in[6];
  const float* w1  = (const float*)d_in[7];
  const float* b1  = (const float*)d_in[8];
  const float* w2  = (const float*)d_in[9];
  const float* b2  = (const float*)d_in[10];
  const float* g1  = (const float*)d_in[11];
  const float* be1 = (const float*)d_in[12];
  const float* g2  = (const float*)d_in[13];
  const float* be2 = (const float*)d_in[14];
  float* out = (float*)d_out;

  float* ws = (float*)d_ws;
  unsigned long long* packed = (unsigned long long*)ws;        // 128 KB
  __hip_bfloat16* Qb = (__hip_bfloat16*)(ws + 32768);          // [96][1024][16] bf16
  __hip_bfloat16* Kb = (__hip_bfloat16*)(ws + 819200);
  __hip_bfloat16* Vt = (__hip_bfloat16*)(ws + 1605632);        // [96][16][1024]
  float* O = ws + 2392064;                                     // [24576][64] f32
  __hip_bfloat16* woP = (__hip_bfloat16*)(ws + 3964928);       // 8192 bf16 (hi+lo)
  __hip_bfloat16* w1P = (__hip_bfloat16*)(ws + 3969024);       // 32768 bf16 (hi+lo)
  __hip_bfloat16* w2P = (__hip_bfloat16*)(ws + 3985408);       // 32768 bf16 (hi+lo)
  float* b1p = ws + 4001792;                                   // 256 f32
  float* biasF = ws + 4002048;                                 // 1M f32 = 4 MB; end ~20.2 MB

  k_pack<<<4096, 256, 0, stream>>>(adj, packed);
  k_bias<<<256, 256, 0, stream>>>((const unsigned*)packed, biasF);
  k_prep<<<19, 256, 0, stream>>>(wo, w1, w2, b1, g2, be2, woP, w1P, w2P, b1p);
  k_ln1_qkv<<<384, 256, 0, stream>>>(x, wq, wk, wv, g1, be1, Qb, Kb, Vt);
  k_attn<<<768, 256, 0, stream>>>(Qb, Kb, Vt, biasF, O);
  k_tail<<<768, 64, 0, stream>>>(O, x, woP, w1P, w2P, bo, b1p, b2, out);
}